// Round 6
// baseline (1012.969 us; speedup 1.0000x reference)
//
#include <hip/hip_runtime.h>
#include <hip/hip_fp16.h>

constexpr int N_NODES  = 500000;
constexpr int N_EDGES  = 8000000;
constexpr int N_GRAPHS = 25000;
constexpr int HID      = 19;

constexpr int NC    = (N_NODES + 1023) / 1024;   // 489 coarse buckets (dst>>10)
constexpr int P1B   = 256;                       // histogram blocks
constexpr int CHUNK = 8192;                      // edges per p2 block
constexpr int P2B   = (N_EDGES + CHUNK - 1) / CHUNK;  // 977
constexpr int NPB   = 13;                        // nodes per 256-thread layer block (13*19=247)

// ---------------- prep: x (11ch,44B) -> xp rows (64B: 11 f32) + pos ----------------
__global__ __launch_bounds__(256)
void prep_kernel(const float* __restrict__ x, float* __restrict__ xp,
                 const int* __restrict__ batch, int* __restrict__ pos) {
    int i = blockIdx.x * 256 + threadIdx.x;
    if (i >= N_NODES) return;
    int b  = batch[i];
    int nb = (i == N_NODES - 1) ? N_GRAPHS : batch[i + 1];
    for (int g = b; g < nb; ++g) pos[g] = i;
    if (i == 0) {
        for (int g = 0; g < b; ++g) pos[g] = N_NODES - 1;   // JAX -1 wrap
    }
    const float* xs = x + (size_t)i * 11;
    float* xd = xp + (size_t)i * 16;
    #pragma unroll
    for (int k = 0; k < 11; ++k) xd[k] = xs[k];
}

// ---------------- P1: per-block coarse histograms ----------------
__global__ __launch_bounds__(256)
void p1_hist(const int* __restrict__ dst, int* __restrict__ blockhist) {
    __shared__ int h[NC];
    int t = threadIdx.x;
    for (int i = t; i < NC; i += 256) h[i] = 0;
    __syncthreads();
    int per = (N_EDGES + P1B - 1) / P1B;
    int s0 = blockIdx.x * per;
    int s1 = min(s0 + per, N_EDGES);
    for (int e = s0 + t; e < s1; e += 256) atomicAdd(&h[dst[e] >> 10], 1);
    __syncthreads();
    for (int i = t; i < NC; i += 256) blockhist[blockIdx.x * NC + i] = h[i];
}

// ---------------- K2a: column totals ----------------
__global__ __launch_bounds__(64)
void k2a_colsum(const int* __restrict__ blockhist, int* __restrict__ coltotal) {
    __shared__ int sh[64];
    int c = blockIdx.x, t = threadIdx.x;
    int s = 0;
    for (int b = t; b < P1B; b += 64) s += blockhist[b * NC + c];
    sh[t] = s;
    __syncthreads();
    for (int off = 32; off > 0; off >>= 1) {
        if (t < off) sh[t] += sh[t + off];
        __syncthreads();
    }
    if (t == 0) coltotal[c] = sh[0];
}

// ---------------- K2b: scan coarse totals ----------------
__global__ __launch_bounds__(512)
void k2b_scan(const int* __restrict__ coltotal, int* __restrict__ coarse_off,
              int* __restrict__ cursor, int* __restrict__ offsets) {
    __shared__ int sh[512];
    int t = threadIdx.x;
    int s = (t < NC) ? coltotal[t] : 0;
    sh[t] = s;
    for (int off = 1; off < 512; off <<= 1) {
        __syncthreads();
        int a = (t >= off) ? sh[t - off] : 0;
        __syncthreads();
        sh[t] += a;
    }
    __syncthreads();
    if (t < NC) { int excl = sh[t] - s; coarse_off[t] = excl; cursor[t] = excl; }
    if (t == 0) { coarse_off[NC] = N_EDGES; offsets[N_NODES] = N_EDGES; }
}

// ---------------- P2: chunked scatter into coarse buckets ----------------
// pack = src | (dst&1023)<<19
__global__ __launch_bounds__(256)
void p2_scatter(const int* __restrict__ src, const int* __restrict__ dst,
                int* __restrict__ cursor, int* __restrict__ bc) {
    __shared__ int h[NC], base[NC];
    int t = threadIdx.x;
    for (int i = t; i < NC; i += 256) h[i] = 0;
    __syncthreads();
    int e0 = blockIdx.x * CHUNK;
    int e1 = min(e0 + CHUNK, N_EDGES);
    for (int e = e0 + t; e < e1; e += 256) atomicAdd(&h[dst[e] >> 10], 1);
    __syncthreads();
    for (int i = t; i < NC; i += 256) {
        int c = h[i];
        base[i] = c ? atomicAdd(&cursor[i], c) : 0;
    }
    __syncthreads();
    for (int i = t; i < NC; i += 256) h[i] = 0;
    __syncthreads();
    for (int e = e0 + t; e < e1; e += 256) {
        int d = dst[e];
        int cb = d >> 10;
        int r = atomicAdd(&h[cb], 1);
        bc[base[cb] + r] = src[e] | ((d & 1023) << 19);
    }
}

// ---------------- P3: node-exact CSR within each coarse bucket ----------------
__global__ __launch_bounds__(256)
void p3_csr(const int* __restrict__ coarse_off, const int* __restrict__ bc,
            int* __restrict__ offsets, int* __restrict__ csr) {
    int c = blockIdx.x;
    int b0 = coarse_off[c], b1 = coarse_off[c + 1];
    __shared__ int h[1024], cur[1024], ts[256];
    int t = threadIdx.x;
    for (int i = t; i < 1024; i += 256) h[i] = 0;
    __syncthreads();
    for (int i = b0 + t; i < b1; i += 256) atomicAdd(&h[(bc[i] >> 19) & 1023], 1);
    __syncthreads();
    int base4 = t * 4;
    int a0 = h[base4], a1 = h[base4 + 1], a2 = h[base4 + 2], a3 = h[base4 + 3];
    int s = a0 + a1 + a2 + a3;
    ts[t] = s;
    for (int off = 1; off < 256; off <<= 1) {
        __syncthreads();
        int v = (t >= off) ? ts[t - off] : 0;
        __syncthreads();
        ts[t] += v;
    }
    __syncthreads();
    int excl = ts[t] - s;
    h[base4]     = excl;
    h[base4 + 1] = excl + a0;
    h[base4 + 2] = excl + a0 + a1;
    h[base4 + 3] = excl + a0 + a1 + a2;
    cur[base4]     = h[base4];
    cur[base4 + 1] = h[base4 + 1];
    cur[base4 + 2] = h[base4 + 2];
    cur[base4 + 3] = h[base4 + 3];
    __syncthreads();
    int node0 = c << 10;
    for (int i = t; i < 1024; i += 256) {
        int n = node0 + i;
        if (n < N_NODES) offsets[n] = b0 + h[i];
    }
    for (int i = b0 + t; i < b1; i += 256) {
        int v = bc[i];
        int loc = (v >> 19) & 1023;
        int p = atomicAdd(&cur[loc], 1);
        csr[b0 + p] = v & 0x7FFFF;
    }
}

// ---------------- combined weights: wc = w0 @ w1[IN:], db = b0 @ w1[IN:] ----------------
__global__ __launch_bounds__(256)
void weights_kernel(const float* w0_1, const float* b0_1, const float* w1_1,
                    const float* w0_2, const float* b0_2, const float* w1_2,
                    const float* w0_3, const float* b0_3, const float* w1_3,
                    float* __restrict__ out) {
    const float *w0, *b0, *w1; int IN;
    if (blockIdx.x == 0)      { w0 = w0_1; b0 = b0_1; w1 = w1_1; IN = 11; }
    else if (blockIdx.x == 1) { w0 = w0_2; b0 = b0_2; w1 = w1_2; IN = 19; }
    else                      { w0 = w0_3; b0 = b0_3; w1 = w1_3; IN = 19; }
    __shared__ float sw0[19 * 19], sw1b[19 * 19], sb0[19];
    int t = threadIdx.x;
    for (int i = t; i < IN * 19; i += 256) sw0[i]  = w0[i];
    for (int i = t; i < 19 * 19; i += 256) sw1b[i] = w1[IN * 19 + i];
    if (t < 19) sb0[t] = b0[t];
    __syncthreads();
    float* o = out + blockIdx.x * 380;
    for (int idx = t; idx < IN * 19; idx += 256) {
        int i = idx / 19, j = idx - 19 * (idx / 19);
        float s = 0.f;
        #pragma unroll
        for (int k = 0; k < 19; ++k) s = fmaf(sw0[i * 19 + k], sw1b[k * 19 + j], s);
        o[idx] = s;
    }
    if (t < 19) {
        float s = 0.f;
        #pragma unroll
        for (int k = 0; k < 19; ++k) s = fmaf(sb0[k], sw1b[k * 19 + t], s);
        o[361 + t] = s;
    }
}

// ---------------- fused layer ----------------
// out = relu(x@w1a + (S@xg)@wc + deg*db + b1 [+ x])
// Gather rows are always 64B-aligned/strided. GPACKED: 13 f32 + 6 f16 layout;
// else plain f32 (channels 0..IN-1 in first 4*IN bytes).
// WPACK: additionally emit packed 64B row of the output for the next layer.
template<int IN, bool RES, bool GPACKED, bool WPACK>
__global__ __launch_bounds__(256)
void fused_layer(const float* __restrict__ x, const char* __restrict__ xg,
                 const int* __restrict__ csr, const int* __restrict__ offsets,
                 const float* __restrict__ w1, const float* __restrict__ b1,
                 const float* __restrict__ wcdb, float* __restrict__ out,
                 char* __restrict__ packout) {
    __shared__ float sw1a[IN * 19], swc[IN * 19], sdb[19], sb1[19];
    __shared__ float shx[NPB][19], shs[NPB][19];
    int t = threadIdx.x;
    for (int i = t; i < IN * 19; i += 256) sw1a[i] = w1[i];
    for (int i = t; i < IN * 19; i += 256) swc[i]  = wcdb[i];
    if (t < 19) { sdb[t] = wcdb[361 + t]; sb1[t] = b1[t]; }
    __syncthreads();
    int g = t / 19, c = t - g * 19;
    int n = blockIdx.x * NPB + g;
    bool active = (t < NPB * 19) && (n < N_NODES);
    int o0 = 0, o1 = 0;
    if (active) {
        o0 = offsets[n]; o1 = offsets[n + 1];
        float xr = 0.f, acc = 0.f;
        if (c < IN) {
            xr = x[(size_t)n * IN + c];
            // per-lane byte offset into a gathered 64B row
            int boff = (!GPACKED || c < 13) ? 4 * c : 52 + 2 * (c - 13);
            int i = o0;
            for (; i + 1 < o1; i += 2) {
                int s0 = csr[i], s1 = csr[i + 1];
                const char* r0 = xg + ((size_t)s0 << 6) + boff;
                const char* r1 = xg + ((size_t)s1 << 6) + boff;
                float v0, v1;
                if (!GPACKED || c < 13) { v0 = *(const float*)r0; v1 = *(const float*)r1; }
                else { v0 = __half2float(*(const __half*)r0); v1 = __half2float(*(const __half*)r1); }
                acc += v0 + v1;
            }
            if (i < o1) {
                const char* r0 = xg + ((size_t)csr[i] << 6) + boff;
                acc += (!GPACKED || c < 13) ? *(const float*)r0
                                            : __half2float(*(const __half*)r0);
            }
        }
        shx[g][c] = xr; shs[g][c] = acc;
    }
    __syncthreads();
    if (active) {
        float v = sb1[c] + (float)(o1 - o0) * sdb[c];
        #pragma unroll
        for (int i = 0; i < IN; ++i) v = fmaf(shx[g][i], sw1a[i * 19 + c], v);
        #pragma unroll
        for (int i = 0; i < IN; ++i) v = fmaf(shs[g][i], swc[i * 19 + c], v);
        if (RES) v += shx[g][c];
        v = fmaxf(v, 0.f);
        out[(size_t)n * 19 + c] = v;
        if (WPACK) {
            char* prow = packout + ((size_t)n << 6);
            if (c < 13) *(float*)(prow + 4 * c) = v;
            else        *(__half*)(prow + 52 + 2 * (c - 13)) = __float2half(v);
        }
    }
}

// ---------------- readout ----------------
__global__ __launch_bounds__(256)
void readout_kernel(const float* __restrict__ h, const int* __restrict__ pos,
                    const float* __restrict__ w0, const float* __restrict__ b0,
                    const float* __restrict__ w1, const float* __restrict__ b1,
                    float* __restrict__ out) {
    __shared__ float ws[HID * 10 + 10 + 10 + 1];
    for (int i = threadIdx.x; i < 211; i += 256) {
        float v;
        if (i < 190)      v = w0[i];
        else if (i < 200) v = b0[i - 190];
        else if (i < 210) v = w1[i - 200];
        else              v = b1[0];
        ws[i] = v;
    }
    __syncthreads();
    int g = blockIdx.x * 256 + threadIdx.x;
    if (g >= N_GRAPHS) return;
    const float* hp = h + (size_t)pos[g] * HID;
    float t[10];
    #pragma unroll
    for (int j = 0; j < 10; ++j) {
        float acc = ws[190 + j];
        #pragma unroll
        for (int i = 0; i < HID; ++i) acc = fmaf(hp[i], ws[i * 10 + j], acc);
        t[j] = fmaxf(acc, 0.0f);
    }
    float o = ws[210];
    #pragma unroll
    for (int j = 0; j < 10; ++j) o = fmaf(t[j], ws[200 + j], o);
    out[g] = fmaxf(o, 0.0f);
}

extern "C" void kernel_launch(void* const* d_in, const int* in_sizes, int n_in,
                              void* d_out, int out_size, void* d_ws, size_t ws_size,
                              hipStream_t stream) {
    const float* x     = (const float*)d_in[0];
    const int*   ei    = (const int*)d_in[1];
    const int*   batch = (const int*)d_in[2];
    const float* w0_1 = (const float*)d_in[3];
    const float* b0_1 = (const float*)d_in[4];
    const float* w1_1 = (const float*)d_in[5];
    const float* b1_1 = (const float*)d_in[6];
    const float* w0_2 = (const float*)d_in[7];
    const float* b0_2 = (const float*)d_in[8];
    const float* w1_2 = (const float*)d_in[9];
    const float* b1_2 = (const float*)d_in[10];
    const float* w0_3 = (const float*)d_in[11];
    const float* b0_3 = (const float*)d_in[12];
    const float* w1_3 = (const float*)d_in[13];
    const float* b1_3 = (const float*)d_in[14];
    const float* wfc0 = (const float*)d_in[15];
    const float* bfc0 = (const float*)d_in[16];
    const float* wfc1 = (const float*)d_in[17];
    const float* bfc1 = (const float*)d_in[18];

    const int* src = ei;            // edge_index[0]
    const int* dst = ei + N_EDGES;  // edge_index[1]

    char* ws = (char*)d_ws;
    size_t off = 0;
    auto alloc = [&](size_t bytes) { void* p = ws + off; off = (off + bytes + 511) & ~(size_t)511; return p; };
    float* BUF_A     = (float*)alloc((size_t)N_NODES * HID * 4);   // 38 MB, f32 h (in-place L2/L3)
    char*  XP        = (char*) alloc((size_t)N_NODES * 64);        // 32 MB: L1 gather rows; reused as pack2
    char*  PACK1     = (char*) alloc((size_t)N_NODES * 64);        // 32 MB: L1 -> L2 packed rows
    int*   csr       = (int*)  alloc((size_t)N_EDGES * 4);         // 32 MB
    int*   offsets   = (int*)  alloc(((size_t)N_NODES + 1) * 4);
    int*   blockhist = (int*)  alloc((size_t)P1B * NC * 4);        // 0.5 MB
    int*   coarse_off= (int*)  alloc((NC + 1) * 4);
    int*   cursor    = (int*)  alloc(NC * 4);
    int*   coltotal  = (int*)  alloc(NC * 4);
    int*   pos       = (int*)  alloc((size_t)N_GRAPHS * 4);
    float* wcdb      = (float*)alloc(3 * 380 * 4);
    // coarse packs dead before L1 writes BUF_A -> alias
    int*   bc        = (int*)BUF_A;
    char*  PACK2     = XP;                                         // XP dead after L1

    dim3 blk(256);
    int gridN = (N_NODES + 255) / 256;
    int gridF = (N_NODES + NPB - 1) / NPB;   // 38462 blocks of 256
    int gridG = (N_GRAPHS + 255) / 256;

    weights_kernel<<<3, blk, 0, stream>>>(w0_1, b0_1, w1_1, w0_2, b0_2, w1_2,
                                          w0_3, b0_3, w1_3, wcdb);
    prep_kernel<<<gridN, blk, 0, stream>>>(x, (float*)XP, batch, pos);

    // ---- bucket sort -> node-exact CSR ----
    p1_hist<<<P1B, blk, 0, stream>>>(dst, blockhist);
    k2a_colsum<<<NC, 64, 0, stream>>>(blockhist, coltotal);
    k2b_scan<<<1, 512, 0, stream>>>(coltotal, coarse_off, cursor, offsets);
    p2_scatter<<<P2B, blk, 0, stream>>>(src, dst, cursor, bc);
    p3_csr<<<NC, blk, 0, stream>>>(coarse_off, bc, offsets, csr);

    // ---- 3 fused layers (1-line packed gathers) ----
    // L1: self x (11ch), gather XP (f32 rows) -> BUF_A f32 + PACK1
    fused_layer<11, false, false, true ><<<gridF, blk, 0, stream>>>(
        x, XP, csr, offsets, w1_1, b1_1, wcdb, BUF_A, PACK1);
    // L2: self BUF_A, gather PACK1 (packed) -> BUF_A in-place + PACK2
    fused_layer<19, true, true, true ><<<gridF, blk, 0, stream>>>(
        BUF_A, PACK1, csr, offsets, w1_2, b1_2, wcdb + 380, BUF_A, PACK2);
    // L3: self BUF_A, gather PACK2 (packed) -> BUF_A in-place
    fused_layer<19, true, true, false><<<gridF, blk, 0, stream>>>(
        BUF_A, PACK2, csr, offsets, w1_3, b1_3, wcdb + 760, BUF_A, nullptr);

    // ---- Readout ----
    readout_kernel<<<gridG, blk, 0, stream>>>(BUF_A, pos, wfc0, bfc0, wfc1, bfc1,
                                              (float*)d_out);
}

// Round 7
// 772.982 us; speedup vs baseline: 1.3105x; 1.3105x over previous
//
#include <hip/hip_runtime.h>
#include <hip/hip_fp16.h>

constexpr int N_NODES  = 500000;
constexpr int N_EDGES  = 8000000;
constexpr int N_GRAPHS = 25000;
constexpr int HID      = 19;

constexpr int NC    = (N_NODES + 1023) / 1024;   // 489 coarse buckets (dst>>10)
constexpr int P1B   = 256;                       // histogram blocks
constexpr int CHUNK = 8192;                      // edges per p2 block
constexpr int P2B   = (N_EDGES + CHUNK - 1) / CHUNK;  // 977
constexpr int LNPB  = 16;                        // nodes per 256-thread layer block

// ---------------- prep: x (11ch,44B) -> xp rows (64B: 11 f32 + pad) + pos ----------------
__global__ __launch_bounds__(256)
void prep_kernel(const float* __restrict__ x, float* __restrict__ xp,
                 const int* __restrict__ batch, int* __restrict__ pos) {
    int i = blockIdx.x * 256 + threadIdx.x;
    if (i >= N_NODES) return;
    int b  = batch[i];
    int nb = (i == N_NODES - 1) ? N_GRAPHS : batch[i + 1];
    for (int g = b; g < nb; ++g) pos[g] = i;
    if (i == 0) {
        for (int g = 0; g < b; ++g) pos[g] = N_NODES - 1;   // JAX -1 wrap
    }
    const float* xs = x + (size_t)i * 11;
    float* xd = xp + (size_t)i * 16;
    #pragma unroll
    for (int k = 0; k < 11; ++k) xd[k] = xs[k];
    #pragma unroll
    for (int k = 11; k < 16; ++k) xd[k] = 0.f;   // keep pad finite
}

// ---------------- P1: per-block coarse histograms ----------------
__global__ __launch_bounds__(256)
void p1_hist(const int* __restrict__ dst, int* __restrict__ blockhist) {
    __shared__ int h[NC];
    int t = threadIdx.x;
    for (int i = t; i < NC; i += 256) h[i] = 0;
    __syncthreads();
    int per = (N_EDGES + P1B - 1) / P1B;
    int s0 = blockIdx.x * per;
    int s1 = min(s0 + per, N_EDGES);
    for (int e = s0 + t; e < s1; e += 256) atomicAdd(&h[dst[e] >> 10], 1);
    __syncthreads();
    for (int i = t; i < NC; i += 256) blockhist[blockIdx.x * NC + i] = h[i];
}

// ---------------- K2a: column totals ----------------
__global__ __launch_bounds__(64)
void k2a_colsum(const int* __restrict__ blockhist, int* __restrict__ coltotal) {
    __shared__ int sh[64];
    int c = blockIdx.x, t = threadIdx.x;
    int s = 0;
    for (int b = t; b < P1B; b += 64) s += blockhist[b * NC + c];
    sh[t] = s;
    __syncthreads();
    for (int off = 32; off > 0; off >>= 1) {
        if (t < off) sh[t] += sh[t + off];
        __syncthreads();
    }
    if (t == 0) coltotal[c] = sh[0];
}

// ---------------- K2b: scan coarse totals ----------------
__global__ __launch_bounds__(512)
void k2b_scan(const int* __restrict__ coltotal, int* __restrict__ coarse_off,
              int* __restrict__ cursor, int* __restrict__ offsets) {
    __shared__ int sh[512];
    int t = threadIdx.x;
    int s = (t < NC) ? coltotal[t] : 0;
    sh[t] = s;
    for (int off = 1; off < 512; off <<= 1) {
        __syncthreads();
        int a = (t >= off) ? sh[t - off] : 0;
        __syncthreads();
        sh[t] += a;
    }
    __syncthreads();
    if (t < NC) { int excl = sh[t] - s; coarse_off[t] = excl; cursor[t] = excl; }
    if (t == 0) { coarse_off[NC] = N_EDGES; offsets[N_NODES] = N_EDGES; }
}

// ---------------- P2: chunked scatter into coarse buckets ----------------
// pack = src | (dst&1023)<<19
__global__ __launch_bounds__(256)
void p2_scatter(const int* __restrict__ src, const int* __restrict__ dst,
                int* __restrict__ cursor, int* __restrict__ bc) {
    __shared__ int h[NC], base[NC];
    int t = threadIdx.x;
    for (int i = t; i < NC; i += 256) h[i] = 0;
    __syncthreads();
    int e0 = blockIdx.x * CHUNK;
    int e1 = min(e0 + CHUNK, N_EDGES);
    for (int e = e0 + t; e < e1; e += 256) atomicAdd(&h[dst[e] >> 10], 1);
    __syncthreads();
    for (int i = t; i < NC; i += 256) {
        int c = h[i];
        base[i] = c ? atomicAdd(&cursor[i], c) : 0;
    }
    __syncthreads();
    for (int i = t; i < NC; i += 256) h[i] = 0;
    __syncthreads();
    for (int e = e0 + t; e < e1; e += 256) {
        int d = dst[e];
        int cb = d >> 10;
        int r = atomicAdd(&h[cb], 1);
        bc[base[cb] + r] = src[e] | ((d & 1023) << 19);
    }
}

// ---------------- P3: node-exact CSR within each coarse bucket ----------------
__global__ __launch_bounds__(256)
void p3_csr(const int* __restrict__ coarse_off, const int* __restrict__ bc,
            int* __restrict__ offsets, int* __restrict__ csr) {
    int c = blockIdx.x;
    int b0 = coarse_off[c], b1 = coarse_off[c + 1];
    __shared__ int h[1024], cur[1024], ts[256];
    int t = threadIdx.x;
    for (int i = t; i < 1024; i += 256) h[i] = 0;
    __syncthreads();
    for (int i = b0 + t; i < b1; i += 256) atomicAdd(&h[(bc[i] >> 19) & 1023], 1);
    __syncthreads();
    int base4 = t * 4;
    int a0 = h[base4], a1 = h[base4 + 1], a2 = h[base4 + 2], a3 = h[base4 + 3];
    int s = a0 + a1 + a2 + a3;
    ts[t] = s;
    for (int off = 1; off < 256; off <<= 1) {
        __syncthreads();
        int v = (t >= off) ? ts[t - off] : 0;
        __syncthreads();
        ts[t] += v;
    }
    __syncthreads();
    int excl = ts[t] - s;
    h[base4]     = excl;
    h[base4 + 1] = excl + a0;
    h[base4 + 2] = excl + a0 + a1;
    h[base4 + 3] = excl + a0 + a1 + a2;
    cur[base4]     = h[base4];
    cur[base4 + 1] = h[base4 + 1];
    cur[base4 + 2] = h[base4 + 2];
    cur[base4 + 3] = h[base4 + 3];
    __syncthreads();
    int node0 = c << 10;
    for (int i = t; i < 1024; i += 256) {
        int n = node0 + i;
        if (n < N_NODES) offsets[n] = b0 + h[i];
    }
    for (int i = b0 + t; i < b1; i += 256) {
        int v = bc[i];
        int loc = (v >> 19) & 1023;
        int p = atomicAdd(&cur[loc], 1);
        csr[b0 + p] = v & 0x7FFFF;
    }
}

// ---------------- combined weights: wc = w0 @ w1[IN:], db = b0 @ w1[IN:] ----------------
__global__ __launch_bounds__(256)
void weights_kernel(const float* w0_1, const float* b0_1, const float* w1_1,
                    const float* w0_2, const float* b0_2, const float* w1_2,
                    const float* w0_3, const float* b0_3, const float* w1_3,
                    float* __restrict__ out) {
    const float *w0, *b0, *w1; int IN;
    if (blockIdx.x == 0)      { w0 = w0_1; b0 = b0_1; w1 = w1_1; IN = 11; }
    else if (blockIdx.x == 1) { w0 = w0_2; b0 = b0_2; w1 = w1_2; IN = 19; }
    else                      { w0 = w0_3; b0 = b0_3; w1 = w1_3; IN = 19; }
    __shared__ float sw0[19 * 19], sw1b[19 * 19], sb0[19];
    int t = threadIdx.x;
    for (int i = t; i < IN * 19; i += 256) sw0[i]  = w0[i];
    for (int i = t; i < 19 * 19; i += 256) sw1b[i] = w1[IN * 19 + i];
    if (t < 19) sb0[t] = b0[t];
    __syncthreads();
    float* o = out + blockIdx.x * 380;
    for (int idx = t; idx < IN * 19; idx += 256) {
        int i = idx / 19, j = idx - 19 * (idx / 19);
        float s = 0.f;
        #pragma unroll
        for (int k = 0; k < 19; ++k) s = fmaf(sw0[i * 19 + k], sw1b[k * 19 + j], s);
        o[idx] = s;
    }
    if (t < 19) {
        float s = 0.f;
        #pragma unroll
        for (int k = 0; k < 19; ++k) s = fmaf(sb0[k], sw1b[k * 19 + t], s);
        o[361 + t] = s;
    }
}

// ---------------- fused layer (float4 gather, 16 lanes/node) ----------------
// out = relu(x@w1a + (S@xg)@wc + deg*db + b1 [+ x])
// Gather rows: 64B aligned. GPACKED: 13 f32 + 6 f16; else 16 f32 (ch 0..IN-1).
// Lane roles within a node's 16 lanes: es = edge slot (0..3), k = 16B quarter (0..3).
template<int IN, bool RES, bool GPACKED, bool WPACK>
__global__ __launch_bounds__(256)
void fused_layer(const float* __restrict__ x, const char* __restrict__ xg,
                 const int* __restrict__ csr, const int* __restrict__ offsets,
                 const float* __restrict__ w1, const float* __restrict__ b1,
                 const float* __restrict__ wcdb, float* __restrict__ out,
                 char* __restrict__ packout) {
    __shared__ float sw1a[IN * 19], swc[IN * 19], sdb[19], sb1[19];
    __shared__ float shx[LNPB][19], shs[LNPB][20];
    __shared__ int   sdeg[LNPB];
    int t = threadIdx.x;
    for (int i = t; i < IN * 19; i += 256) { sw1a[i] = w1[i]; swc[i] = wcdb[i]; }
    if (t < 19) { sdb[t] = wcdb[361 + t]; sb1[t] = b1[t]; }
    int node0 = blockIdx.x * LNPB;
    // self rows -> LDS (coalesced stream)
    for (int idx = t; idx < LNPB * IN; idx += 256) {
        int nl = idx / IN, i = idx - nl * IN;
        shx[nl][i] = x[(size_t)(node0 + nl) * IN + i];
    }
    int nl = t >> 4;              // node within block (0..15)
    int l16 = t & 15;
    int es = l16 >> 2, k = l16 & 3;
    int n = node0 + nl;           // always < N_NODES (500000 = 16*31250)
    float acc[8] = {0.f, 0.f, 0.f, 0.f, 0.f, 0.f, 0.f, 0.f};
    int o0 = offsets[n], o1 = offsets[n + 1];
    for (int i = o0 + es; i < o1; i += 4) {
        int row = csr[i];
        const float4 v = *(const float4*)(xg + ((size_t)row << 6) + (k << 4));
        if (GPACKED && k == 3) {
            acc[0] += v.x;                          // ch12 (f32)
            const __half2* hp = (const __half2*)&v.y;
            float2 a = __half22float2(hp[0]);
            float2 b = __half22float2(hp[1]);
            float2 c = __half22float2(hp[2]);
            acc[1] += a.x; acc[2] += a.y;
            acc[3] += b.x; acc[4] += b.y;
            acc[5] += c.x; acc[6] += c.y;
        } else {
            acc[0] += v.x; acc[1] += v.y; acc[2] += v.z; acc[3] += v.w;
        }
    }
    // fold the 4 edge slots (lane ^4, ^8 within each 16-lane group)
    #pragma unroll
    for (int j = 0; j < 8; ++j) {
        acc[j] += __shfl_xor(acc[j], 4);
        acc[j] += __shfl_xor(acc[j], 8);
    }
    if (es == 0) {
        if (GPACKED && k == 3) {
            shs[nl][12] = acc[0];
            #pragma unroll
            for (int j = 0; j < 6; ++j) shs[nl][13 + j] = acc[1 + j];
        } else {
            #pragma unroll
            for (int j = 0; j < 4; ++j) {
                int ch = 4 * k + j;
                if (ch < 19) shs[nl][ch] = acc[j];
            }
        }
        if (k == 0) sdeg[nl] = o1 - o0;
    }
    __syncthreads();
    for (int idx = t; idx < LNPB * 19; idx += 256) {
        int nl2 = idx / 19, cc = idx - nl2 * 19;
        int n2 = node0 + nl2;
        float v = sb1[cc] + (float)sdeg[nl2] * sdb[cc];
        #pragma unroll
        for (int i = 0; i < IN; ++i) v = fmaf(shx[nl2][i], sw1a[i * 19 + cc], v);
        #pragma unroll
        for (int i = 0; i < IN; ++i) v = fmaf(shs[nl2][i], swc[i * 19 + cc], v);
        if (RES) v += shx[nl2][cc];
        v = fmaxf(v, 0.f);
        out[(size_t)n2 * 19 + cc] = v;
        if (WPACK) {
            char* prow = packout + ((size_t)n2 << 6);
            if (cc < 13) *(float*)(prow + 4 * cc) = v;
            else         *(__half*)(prow + 52 + 2 * (cc - 13)) = __float2half(v);
        }
    }
}

// ---------------- readout ----------------
__global__ __launch_bounds__(256)
void readout_kernel(const float* __restrict__ h, const int* __restrict__ pos,
                    const float* __restrict__ w0, const float* __restrict__ b0,
                    const float* __restrict__ w1, const float* __restrict__ b1,
                    float* __restrict__ out) {
    __shared__ float ws[HID * 10 + 10 + 10 + 1];
    for (int i = threadIdx.x; i < 211; i += 256) {
        float v;
        if (i < 190)      v = w0[i];
        else if (i < 200) v = b0[i - 190];
        else if (i < 210) v = w1[i - 200];
        else              v = b1[0];
        ws[i] = v;
    }
    __syncthreads();
    int g = blockIdx.x * 256 + threadIdx.x;
    if (g >= N_GRAPHS) return;
    const float* hp = h + (size_t)pos[g] * HID;
    float t[10];
    #pragma unroll
    for (int j = 0; j < 10; ++j) {
        float acc = ws[190 + j];
        #pragma unroll
        for (int i = 0; i < HID; ++i) acc = fmaf(hp[i], ws[i * 10 + j], acc);
        t[j] = fmaxf(acc, 0.0f);
    }
    float o = ws[210];
    #pragma unroll
    for (int j = 0; j < 10; ++j) o = fmaf(t[j], ws[200 + j], o);
    out[g] = fmaxf(o, 0.0f);
}

extern "C" void kernel_launch(void* const* d_in, const int* in_sizes, int n_in,
                              void* d_out, int out_size, void* d_ws, size_t ws_size,
                              hipStream_t stream) {
    const float* x     = (const float*)d_in[0];
    const int*   ei    = (const int*)d_in[1];
    const int*   batch = (const int*)d_in[2];
    const float* w0_1 = (const float*)d_in[3];
    const float* b0_1 = (const float*)d_in[4];
    const float* w1_1 = (const float*)d_in[5];
    const float* b1_1 = (const float*)d_in[6];
    const float* w0_2 = (const float*)d_in[7];
    const float* b0_2 = (const float*)d_in[8];
    const float* w1_2 = (const float*)d_in[9];
    const float* b1_2 = (const float*)d_in[10];
    const float* w0_3 = (const float*)d_in[11];
    const float* b0_3 = (const float*)d_in[12];
    const float* w1_3 = (const float*)d_in[13];
    const float* b1_3 = (const float*)d_in[14];
    const float* wfc0 = (const float*)d_in[15];
    const float* bfc0 = (const float*)d_in[16];
    const float* wfc1 = (const float*)d_in[17];
    const float* bfc1 = (const float*)d_in[18];

    const int* src = ei;            // edge_index[0]
    const int* dst = ei + N_EDGES;  // edge_index[1]

    char* ws = (char*)d_ws;
    size_t off = 0;
    auto alloc = [&](size_t bytes) { void* p = ws + off; off = (off + bytes + 511) & ~(size_t)511; return p; };
    float* BUF_A     = (float*)alloc((size_t)N_NODES * HID * 4);   // 38 MB (L1 out, L3 out)
    float* BUF_C     = (float*)alloc((size_t)N_NODES * HID * 4);   // 38 MB (L2 out)
    char*  XP        = (char*) alloc((size_t)N_NODES * 64);        // 32 MB: L1 gather rows; reused as PACK2
    char*  PACK1     = (char*) alloc((size_t)N_NODES * 64);        // 32 MB: L1 -> L2 packed rows
    int*   csr       = (int*)  alloc((size_t)N_EDGES * 4);         // 32 MB
    int*   offsets   = (int*)  alloc(((size_t)N_NODES + 1) * 4);
    int*   blockhist = (int*)  alloc((size_t)P1B * NC * 4);        // 0.5 MB
    int*   coarse_off= (int*)  alloc((NC + 1) * 4);
    int*   cursor    = (int*)  alloc(NC * 4);
    int*   coltotal  = (int*)  alloc(NC * 4);
    int*   pos       = (int*)  alloc((size_t)N_GRAPHS * 4);
    float* wcdb      = (float*)alloc(3 * 380 * 4);
    // aliases: bc (coarse packs) dead before L1 writes BUF_A; XP dead after L1
    int*   bc        = (int*)BUF_A;
    char*  PACK2     = XP;

    dim3 blk(256);
    int gridN = (N_NODES + 255) / 256;
    int gridL = N_NODES / LNPB;              // 31250, exact
    int gridG = (N_GRAPHS + 255) / 256;

    weights_kernel<<<3, blk, 0, stream>>>(w0_1, b0_1, w1_1, w0_2, b0_2, w1_2,
                                          w0_3, b0_3, w1_3, wcdb);
    prep_kernel<<<gridN, blk, 0, stream>>>(x, (float*)XP, batch, pos);

    // ---- bucket sort -> node-exact CSR ----
    p1_hist<<<P1B, blk, 0, stream>>>(dst, blockhist);
    k2a_colsum<<<NC, 64, 0, stream>>>(blockhist, coltotal);
    k2b_scan<<<1, 512, 0, stream>>>(coltotal, coarse_off, cursor, offsets);
    p2_scatter<<<P2B, blk, 0, stream>>>(src, dst, cursor, bc);
    p3_csr<<<NC, blk, 0, stream>>>(coarse_off, bc, offsets, csr);

    // ---- 3 fused layers (float4 1-line gathers) ----
    // L1: self x (11ch), gather XP (16 f32 rows) -> BUF_A + PACK1
    fused_layer<11, false, false, true ><<<gridL, blk, 0, stream>>>(
        x, XP, csr, offsets, w1_1, b1_1, wcdb, BUF_A, PACK1);
    // L2: self BUF_A, gather PACK1 -> BUF_C + PACK2
    fused_layer<19, true, true, true ><<<gridL, blk, 0, stream>>>(
        BUF_A, PACK1, csr, offsets, w1_2, b1_2, wcdb + 380, BUF_C, PACK2);
    // L3: self BUF_C, gather PACK2 -> BUF_A
    fused_layer<19, true, true, false><<<gridL, blk, 0, stream>>>(
        BUF_C, PACK2, csr, offsets, w1_3, b1_3, wcdb + 760, BUF_A, nullptr);

    // ---- Readout ----
    readout_kernel<<<gridG, blk, 0, stream>>>(BUF_A, pos, wfc0, bfc0, wfc1, bfc1,
                                              (float*)d_out);
}

// Round 8
// 739.064 us; speedup vs baseline: 1.3706x; 1.0459x over previous
//
#include <hip/hip_runtime.h>
#include <hip/hip_fp16.h>

constexpr int N_NODES  = 500000;
constexpr int N_EDGES  = 8000000;
constexpr int N_GRAPHS = 25000;
constexpr int HID      = 19;

constexpr int NC    = (N_NODES + 1023) / 1024;   // 489 coarse buckets (dst>>10)
constexpr int P1B   = 256;                       // histogram blocks
constexpr int CHUNK = 8192;                      // edges per p2 block
constexpr int P2B   = (N_EDGES + CHUNK - 1) / CHUNK;  // 977
constexpr int LNPB  = 16;                        // nodes per 256-thread layer block

// ---------------- prep: x (11ch,44B) -> xp rows (64B: 11 f32 + pad) + pos ----------------
__global__ __launch_bounds__(256)
void prep_kernel(const float* __restrict__ x, float* __restrict__ xp,
                 const int* __restrict__ batch, int* __restrict__ pos) {
    int i = blockIdx.x * 256 + threadIdx.x;
    if (i >= N_NODES) return;
    int b  = batch[i];
    int nb = (i == N_NODES - 1) ? N_GRAPHS : batch[i + 1];
    for (int g = b; g < nb; ++g) pos[g] = i;
    if (i == 0) {
        for (int g = 0; g < b; ++g) pos[g] = N_NODES - 1;   // JAX -1 wrap
    }
    const float* xs = x + (size_t)i * 11;
    float* xd = xp + (size_t)i * 16;
    #pragma unroll
    for (int k = 0; k < 11; ++k) xd[k] = xs[k];
    #pragma unroll
    for (int k = 11; k < 16; ++k) xd[k] = 0.f;   // keep pad finite
}

// ---------------- P1: per-block coarse histograms ----------------
__global__ __launch_bounds__(256)
void p1_hist(const int* __restrict__ dst, int* __restrict__ blockhist) {
    __shared__ int h[NC];
    int t = threadIdx.x;
    for (int i = t; i < NC; i += 256) h[i] = 0;
    __syncthreads();
    int per = (N_EDGES + P1B - 1) / P1B;
    int s0 = blockIdx.x * per;
    int s1 = min(s0 + per, N_EDGES);
    for (int e = s0 + t; e < s1; e += 256) atomicAdd(&h[dst[e] >> 10], 1);
    __syncthreads();
    for (int i = t; i < NC; i += 256) blockhist[blockIdx.x * NC + i] = h[i];
}

// ---------------- K2a: column totals ----------------
__global__ __launch_bounds__(64)
void k2a_colsum(const int* __restrict__ blockhist, int* __restrict__ coltotal) {
    __shared__ int sh[64];
    int c = blockIdx.x, t = threadIdx.x;
    int s = 0;
    for (int b = t; b < P1B; b += 64) s += blockhist[b * NC + c];
    sh[t] = s;
    __syncthreads();
    for (int off = 32; off > 0; off >>= 1) {
        if (t < off) sh[t] += sh[t + off];
        __syncthreads();
    }
    if (t == 0) coltotal[c] = sh[0];
}

// ---------------- K2b: scan coarse totals ----------------
__global__ __launch_bounds__(512)
void k2b_scan(const int* __restrict__ coltotal, int* __restrict__ coarse_off,
              int* __restrict__ cursor, int* __restrict__ offsets) {
    __shared__ int sh[512];
    int t = threadIdx.x;
    int s = (t < NC) ? coltotal[t] : 0;
    sh[t] = s;
    for (int off = 1; off < 512; off <<= 1) {
        __syncthreads();
        int a = (t >= off) ? sh[t - off] : 0;
        __syncthreads();
        sh[t] += a;
    }
    __syncthreads();
    if (t < NC) { int excl = sh[t] - s; coarse_off[t] = excl; cursor[t] = excl; }
    if (t == 0) { coarse_off[NC] = N_EDGES; offsets[N_NODES] = N_EDGES; }
}

// ---------------- P2: chunked scatter, LDS-staged + coalesced write-out ----------------
// pack = src | (dst&1023)<<19
__global__ __launch_bounds__(256)
void p2_scatter(const int* __restrict__ src, const int* __restrict__ dst,
                int* __restrict__ cursor, int* __restrict__ bc) {
    __shared__ int h[NC], lh[NC], base[NC], cur[NC];
    __shared__ int sc[512];
    __shared__ int sorted[CHUNK];
    __shared__ unsigned short bkt[CHUNK];
    int t = threadIdx.x;
    for (int i = t; i < NC; i += 256) h[i] = 0;
    __syncthreads();
    int e0 = blockIdx.x * CHUNK;
    int e1 = min(e0 + CHUNK, N_EDGES);
    int ne = e1 - e0;
    // pass 1: histogram
    for (int e = e0 + t; e < e1; e += 256) atomicAdd(&h[dst[e] >> 10], 1);
    __syncthreads();
    // in-block exclusive scan of h (489 entries, 2 per thread)
    int v0 = (t < NC) ? h[t] : 0;
    int v1 = (t + 256 < NC) ? h[t + 256] : 0;
    sc[t] = v0; sc[t + 256] = v1;
    for (int off = 1; off < 512; off <<= 1) {
        __syncthreads();
        int a = (t >= off) ? sc[t - off] : 0;
        int b = (t + 256 >= off) ? sc[t + 256 - off] : 0;
        __syncthreads();
        sc[t] += a; sc[t + 256] += b;
    }
    __syncthreads();
    // lh = exclusive scan; reserve global chunk per touched bucket
    if (t < NC) {
        lh[t] = sc[t] - v0; cur[t] = sc[t] - v0;
        base[t] = v0 ? atomicAdd(&cursor[t], v0) : 0;
    }
    if (t + 256 < NC) {
        lh[t + 256] = sc[t + 256] - v1; cur[t + 256] = sc[t + 256] - v1;
        base[t + 256] = v1 ? atomicAdd(&cursor[t + 256], v1) : 0;
    }
    __syncthreads();
    // pass 2: scatter into LDS, grouped by bucket
    for (int e = e0 + t; e < e1; e += 256) {
        int d = dst[e];
        int cb = d >> 10;
        int r = atomicAdd(&cur[cb], 1);
        sorted[r] = src[e] | ((d & 1023) << 19);
        bkt[r] = (unsigned short)cb;
    }
    __syncthreads();
    // write-out: consecutive threads -> consecutive addresses within each run
    for (int p = t; p < ne; p += 256) {
        int cb = bkt[p];
        bc[base[cb] + (p - lh[cb])] = sorted[p];
    }
}

// ---------------- P3: node-exact CSR within each coarse bucket ----------------
__global__ __launch_bounds__(256)
void p3_csr(const int* __restrict__ coarse_off, const int* __restrict__ bc,
            int* __restrict__ offsets, int* __restrict__ csr) {
    int c = blockIdx.x;
    int b0 = coarse_off[c], b1 = coarse_off[c + 1];
    __shared__ int h[1024], cur[1024], ts[256];
    int t = threadIdx.x;
    for (int i = t; i < 1024; i += 256) h[i] = 0;
    __syncthreads();
    for (int i = b0 + t; i < b1; i += 256) atomicAdd(&h[(bc[i] >> 19) & 1023], 1);
    __syncthreads();
    int base4 = t * 4;
    int a0 = h[base4], a1 = h[base4 + 1], a2 = h[base4 + 2], a3 = h[base4 + 3];
    int s = a0 + a1 + a2 + a3;
    ts[t] = s;
    for (int off = 1; off < 256; off <<= 1) {
        __syncthreads();
        int v = (t >= off) ? ts[t - off] : 0;
        __syncthreads();
        ts[t] += v;
    }
    __syncthreads();
    int excl = ts[t] - s;
    h[base4]     = excl;
    h[base4 + 1] = excl + a0;
    h[base4 + 2] = excl + a0 + a1;
    h[base4 + 3] = excl + a0 + a1 + a2;
    cur[base4]     = h[base4];
    cur[base4 + 1] = h[base4 + 1];
    cur[base4 + 2] = h[base4 + 2];
    cur[base4 + 3] = h[base4 + 3];
    __syncthreads();
    int node0 = c << 10;
    for (int i = t; i < 1024; i += 256) {
        int n = node0 + i;
        if (n < N_NODES) offsets[n] = b0 + h[i];
    }
    for (int i = b0 + t; i < b1; i += 256) {
        int v = bc[i];
        int loc = (v >> 19) & 1023;
        int p = atomicAdd(&cur[loc], 1);
        csr[b0 + p] = v & 0x7FFFF;
    }
}

// ---------------- combined weights: wc = w0 @ w1[IN:], db = b0 @ w1[IN:] ----------------
__global__ __launch_bounds__(256)
void weights_kernel(const float* w0_1, const float* b0_1, const float* w1_1,
                    const float* w0_2, const float* b0_2, const float* w1_2,
                    const float* w0_3, const float* b0_3, const float* w1_3,
                    float* __restrict__ out) {
    const float *w0, *b0, *w1; int IN;
    if (blockIdx.x == 0)      { w0 = w0_1; b0 = b0_1; w1 = w1_1; IN = 11; }
    else if (blockIdx.x == 1) { w0 = w0_2; b0 = b0_2; w1 = w1_2; IN = 19; }
    else                      { w0 = w0_3; b0 = b0_3; w1 = w1_3; IN = 19; }
    __shared__ float sw0[19 * 19], sw1b[19 * 19], sb0[19];
    int t = threadIdx.x;
    for (int i = t; i < IN * 19; i += 256) sw0[i]  = w0[i];
    for (int i = t; i < 19 * 19; i += 256) sw1b[i] = w1[IN * 19 + i];
    if (t < 19) sb0[t] = b0[t];
    __syncthreads();
    float* o = out + blockIdx.x * 380;
    for (int idx = t; idx < IN * 19; idx += 256) {
        int i = idx / 19, j = idx - 19 * (idx / 19);
        float s = 0.f;
        #pragma unroll
        for (int k = 0; k < 19; ++k) s = fmaf(sw0[i * 19 + k], sw1b[k * 19 + j], s);
        o[idx] = s;
    }
    if (t < 19) {
        float s = 0.f;
        #pragma unroll
        for (int k = 0; k < 19; ++k) s = fmaf(sb0[k], sw1b[k * 19 + t], s);
        o[361 + t] = s;
    }
}

// ---------------- fused layer (float4 gather, 16 lanes/node) ----------------
// out = relu(x@w1a + (S@xg)@wc + deg*db + b1 [+ x])
// Gather rows: 64B aligned. GPACKED: 13 f32 + 6 f16; else 16 f32 (ch 0..IN-1).
// Lane roles within a node's 16 lanes: es = edge slot (0..3), k = 16B quarter (0..3).
template<int IN, bool RES, bool GPACKED, bool WPACK>
__global__ __launch_bounds__(256)
void fused_layer(const float* __restrict__ x, const char* __restrict__ xg,
                 const int* __restrict__ csr, const int* __restrict__ offsets,
                 const float* __restrict__ w1, const float* __restrict__ b1,
                 const float* __restrict__ wcdb, float* __restrict__ out,
                 char* __restrict__ packout) {
    __shared__ float sw1a[IN * 19], swc[IN * 19], sdb[19], sb1[19];
    __shared__ float shx[LNPB][19], shs[LNPB][20];
    __shared__ int   sdeg[LNPB];
    int t = threadIdx.x;
    for (int i = t; i < IN * 19; i += 256) { sw1a[i] = w1[i]; swc[i] = wcdb[i]; }
    if (t < 19) { sdb[t] = wcdb[361 + t]; sb1[t] = b1[t]; }
    int node0 = blockIdx.x * LNPB;
    // self rows -> LDS (coalesced stream)
    for (int idx = t; idx < LNPB * IN; idx += 256) {
        int nl = idx / IN, i = idx - nl * IN;
        shx[nl][i] = x[(size_t)(node0 + nl) * IN + i];
    }
    int nl = t >> 4;              // node within block (0..15)
    int l16 = t & 15;
    int es = l16 >> 2, k = l16 & 3;
    int n = node0 + nl;           // always < N_NODES (500000 = 16*31250)
    float acc[8] = {0.f, 0.f, 0.f, 0.f, 0.f, 0.f, 0.f, 0.f};
    int o0 = offsets[n], o1 = offsets[n + 1];
    for (int i = o0 + es; i < o1; i += 4) {
        int row = csr[i];
        const float4 v = *(const float4*)(xg + ((size_t)row << 6) + (k << 4));
        if (GPACKED && k == 3) {
            acc[0] += v.x;                          // ch12 (f32)
            const __half2* hp = (const __half2*)&v.y;
            float2 a = __half22float2(hp[0]);
            float2 b = __half22float2(hp[1]);
            float2 c = __half22float2(hp[2]);
            acc[1] += a.x; acc[2] += a.y;
            acc[3] += b.x; acc[4] += b.y;
            acc[5] += c.x; acc[6] += c.y;
        } else {
            acc[0] += v.x; acc[1] += v.y; acc[2] += v.z; acc[3] += v.w;
        }
    }
    // fold the 4 edge slots (lane ^4, ^8 within each 16-lane group)
    #pragma unroll
    for (int j = 0; j < 8; ++j) {
        acc[j] += __shfl_xor(acc[j], 4);
        acc[j] += __shfl_xor(acc[j], 8);
    }
    if (es == 0) {
        if (GPACKED && k == 3) {
            shs[nl][12] = acc[0];
            #pragma unroll
            for (int j = 0; j < 6; ++j) shs[nl][13 + j] = acc[1 + j];
        } else {
            #pragma unroll
            for (int j = 0; j < 4; ++j) {
                int ch = 4 * k + j;
                if (ch < 19) shs[nl][ch] = acc[j];
            }
        }
        if (k == 0) sdeg[nl] = o1 - o0;
    }
    __syncthreads();
    for (int idx = t; idx < LNPB * 19; idx += 256) {
        int nl2 = idx / 19, cc = idx - nl2 * 19;
        int n2 = node0 + nl2;
        float v = sb1[cc] + (float)sdeg[nl2] * sdb[cc];
        #pragma unroll
        for (int i = 0; i < IN; ++i) v = fmaf(shx[nl2][i], sw1a[i * 19 + cc], v);
        #pragma unroll
        for (int i = 0; i < IN; ++i) v = fmaf(shs[nl2][i], swc[i * 19 + cc], v);
        if (RES) v += shx[nl2][cc];
        v = fmaxf(v, 0.f);
        out[(size_t)n2 * 19 + cc] = v;
        if (WPACK) {
            char* prow = packout + ((size_t)n2 << 6);
            if (cc < 13) *(float*)(prow + 4 * cc) = v;
            else         *(__half*)(prow + 52 + 2 * (cc - 13)) = __float2half(v);
        }
    }
}

// ---------------- readout ----------------
__global__ __launch_bounds__(256)
void readout_kernel(const float* __restrict__ h, const int* __restrict__ pos,
                    const float* __restrict__ w0, const float* __restrict__ b0,
                    const float* __restrict__ w1, const float* __restrict__ b1,
                    float* __restrict__ out) {
    __shared__ float ws[HID * 10 + 10 + 10 + 1];
    for (int i = threadIdx.x; i < 211; i += 256) {
        float v;
        if (i < 190)      v = w0[i];
        else if (i < 200) v = b0[i - 190];
        else if (i < 210) v = w1[i - 200];
        else              v = b1[0];
        ws[i] = v;
    }
    __syncthreads();
    int g = blockIdx.x * 256 + threadIdx.x;
    if (g >= N_GRAPHS) return;
    const float* hp = h + (size_t)pos[g] * HID;
    float t[10];
    #pragma unroll
    for (int j = 0; j < 10; ++j) {
        float acc = ws[190 + j];
        #pragma unroll
        for (int i = 0; i < HID; ++i) acc = fmaf(hp[i], ws[i * 10 + j], acc);
        t[j] = fmaxf(acc, 0.0f);
    }
    float o = ws[210];
    #pragma unroll
    for (int j = 0; j < 10; ++j) o = fmaf(t[j], ws[200 + j], o);
    out[g] = fmaxf(o, 0.0f);
}

extern "C" void kernel_launch(void* const* d_in, const int* in_sizes, int n_in,
                              void* d_out, int out_size, void* d_ws, size_t ws_size,
                              hipStream_t stream) {
    const float* x     = (const float*)d_in[0];
    const int*   ei    = (const int*)d_in[1];
    const int*   batch = (const int*)d_in[2];
    const float* w0_1 = (const float*)d_in[3];
    const float* b0_1 = (const float*)d_in[4];
    const float* w1_1 = (const float*)d_in[5];
    const float* b1_1 = (const float*)d_in[6];
    const float* w0_2 = (const float*)d_in[7];
    const float* b0_2 = (const float*)d_in[8];
    const float* w1_2 = (const float*)d_in[9];
    const float* b1_2 = (const float*)d_in[10];
    const float* w0_3 = (const float*)d_in[11];
    const float* b0_3 = (const float*)d_in[12];
    const float* w1_3 = (const float*)d_in[13];
    const float* b1_3 = (const float*)d_in[14];
    const float* wfc0 = (const float*)d_in[15];
    const float* bfc0 = (const float*)d_in[16];
    const float* wfc1 = (const float*)d_in[17];
    const float* bfc1 = (const float*)d_in[18];

    const int* src = ei;            // edge_index[0]
    const int* dst = ei + N_EDGES;  // edge_index[1]

    char* ws = (char*)d_ws;
    size_t off = 0;
    auto alloc = [&](size_t bytes) { void* p = ws + off; off = (off + bytes + 511) & ~(size_t)511; return p; };
    float* BUF_A     = (float*)alloc((size_t)N_NODES * HID * 4);   // 38 MB (L1 out, L3 out)
    float* BUF_C     = (float*)alloc((size_t)N_NODES * HID * 4);   // 38 MB (L2 out)
    char*  XP        = (char*) alloc((size_t)N_NODES * 64);        // 32 MB: L1 gather rows; reused as PACK2
    char*  PACK1     = (char*) alloc((size_t)N_NODES * 64);        // 32 MB: L1 -> L2 packed rows
    int*   csr       = (int*)  alloc((size_t)N_EDGES * 4);         // 32 MB
    int*   offsets   = (int*)  alloc(((size_t)N_NODES + 1) * 4);
    int*   blockhist = (int*)  alloc((size_t)P1B * NC * 4);        // 0.5 MB
    int*   coarse_off= (int*)  alloc((NC + 1) * 4);
    int*   cursor    = (int*)  alloc(NC * 4);
    int*   coltotal  = (int*)  alloc(NC * 4);
    int*   pos       = (int*)  alloc((size_t)N_GRAPHS * 4);
    float* wcdb      = (float*)alloc(3 * 380 * 4);
    // aliases: bc (coarse packs) dead before L1 writes BUF_A; XP dead after L1
    int*   bc        = (int*)BUF_A;
    char*  PACK2     = XP;

    dim3 blk(256);
    int gridN = (N_NODES + 255) / 256;
    int gridL = N_NODES / LNPB;              // 31250, exact
    int gridG = (N_GRAPHS + 255) / 256;

    weights_kernel<<<3, blk, 0, stream>>>(w0_1, b0_1, w1_1, w0_2, b0_2, w1_2,
                                          w0_3, b0_3, w1_3, wcdb);
    prep_kernel<<<gridN, blk, 0, stream>>>(x, (float*)XP, batch, pos);

    // ---- bucket sort -> node-exact CSR ----
    p1_hist<<<P1B, blk, 0, stream>>>(dst, blockhist);
    k2a_colsum<<<NC, 64, 0, stream>>>(blockhist, coltotal);
    k2b_scan<<<1, 512, 0, stream>>>(coltotal, coarse_off, cursor, offsets);
    p2_scatter<<<P2B, blk, 0, stream>>>(src, dst, cursor, bc);
    p3_csr<<<NC, blk, 0, stream>>>(coarse_off, bc, offsets, csr);

    // ---- 3 fused layers (float4 1-line gathers) ----
    // L1: self x (11ch), gather XP (16 f32 rows) -> BUF_A + PACK1
    fused_layer<11, false, false, true ><<<gridL, blk, 0, stream>>>(
        x, XP, csr, offsets, w1_1, b1_1, wcdb, BUF_A, PACK1);
    // L2: self BUF_A, gather PACK1 -> BUF_C + PACK2
    fused_layer<19, true, true, true ><<<gridL, blk, 0, stream>>>(
        BUF_A, PACK1, csr, offsets, w1_2, b1_2, wcdb + 380, BUF_C, PACK2);
    // L3: self BUF_C, gather PACK2 -> BUF_A
    fused_layer<19, true, true, false><<<gridL, blk, 0, stream>>>(
        BUF_C, PACK2, csr, offsets, w1_3, b1_3, wcdb + 760, BUF_A, nullptr);

    // ---- Readout ----
    readout_kernel<<<gridG, blk, 0, stream>>>(BUF_A, pos, wfc0, bfc0, wfc1, bfc1,
                                              (float*)d_out);
}

// Round 9
// 668.379 us; speedup vs baseline: 1.5156x; 1.1058x over previous
//
#include <hip/hip_runtime.h>
#include <hip/hip_fp16.h>

constexpr int N_NODES  = 500000;
constexpr int N_EDGES  = 8000000;
constexpr int N_GRAPHS = 25000;
constexpr int HID      = 19;

constexpr int NC    = (N_NODES + 1023) / 1024;   // 489 coarse buckets (dst>>10)
constexpr int CHUNK = 8192;                      // edges per sort chunk
constexpr int P2B   = (N_EDGES + CHUNK - 1) / CHUNK;  // 977 chunks
constexpr int LNPB  = 16;                        // nodes per 256-thread layer block

// ---------------- prep: x (11ch f32) -> xp rows (32B: 11 f16 + pad) + pos ----------------
__global__ __launch_bounds__(256)
void prep_kernel(const float* __restrict__ x, __half* __restrict__ xp,
                 const int* __restrict__ batch, int* __restrict__ pos) {
    int i = blockIdx.x * 256 + threadIdx.x;
    if (i >= N_NODES) return;
    int b  = batch[i];
    int nb = (i == N_NODES - 1) ? N_GRAPHS : batch[i + 1];
    for (int g = b; g < nb; ++g) pos[g] = i;
    if (i == 0) {
        for (int g = 0; g < b; ++g) pos[g] = N_NODES - 1;   // JAX -1 wrap
    }
    const float* xs = x + (size_t)i * 11;
    __half* xd = xp + (size_t)i * 16;
    #pragma unroll
    for (int k = 0; k < 11; ++k) xd[k] = __float2half(xs[k]);
    #pragma unroll
    for (int k = 11; k < 16; ++k) xd[k] = __half(0.0f);
}

// ---------------- P1: per-chunk coarse histograms ----------------
__global__ __launch_bounds__(256)
void p1_hist(const int* __restrict__ dst, int* __restrict__ chunkhist) {
    __shared__ int h[NC];
    int t = threadIdx.x, k = blockIdx.x;
    for (int i = t; i < NC; i += 256) h[i] = 0;
    __syncthreads();
    int e0 = k * CHUNK;
    int e1 = min(e0 + CHUNK, N_EDGES);
    for (int e = e0 + t; e < e1; e += 256) atomicAdd(&h[dst[e] >> 10], 1);
    __syncthreads();
    for (int i = t; i < NC; i += 256) chunkhist[(size_t)k * NC + i] = h[i];
}

// ---------------- KA: per-bucket exclusive scan across chunks ----------------
__global__ __launch_bounds__(256)
void ka_chunkscan(const int* __restrict__ chunkhist, int* __restrict__ chunkpre,
                  int* __restrict__ coltotal) {
    int c = blockIdx.x, t = threadIdx.x;
    int v[4];
    #pragma unroll
    for (int j = 0; j < 4; ++j) {
        int k = 4 * t + j;
        v[j] = (k < P2B) ? chunkhist[(size_t)k * NC + c] : 0;
    }
    int s = v[0] + v[1] + v[2] + v[3];
    __shared__ int sc[256];
    sc[t] = s;
    for (int off = 1; off < 256; off <<= 1) {
        __syncthreads();
        int a = (t >= off) ? sc[t - off] : 0;
        __syncthreads();
        sc[t] += a;
    }
    __syncthreads();
    int run = sc[t] - s;   // exclusive over threads
    #pragma unroll
    for (int j = 0; j < 4; ++j) {
        int k = 4 * t + j;
        if (k < P2B) chunkpre[(size_t)k * NC + c] = run;
        run += v[j];
    }
    if (t == 255) coltotal[c] = run;
}

// ---------------- KB: scan bucket totals -> coarse_off ----------------
__global__ __launch_bounds__(512)
void kb_scan(const int* __restrict__ coltotal, int* __restrict__ coarse_off,
             int* __restrict__ offsets) {
    __shared__ int sh[512];
    int t = threadIdx.x;
    int s = (t < NC) ? coltotal[t] : 0;
    sh[t] = s;
    for (int off = 1; off < 512; off <<= 1) {
        __syncthreads();
        int a = (t >= off) ? sh[t - off] : 0;
        __syncthreads();
        sh[t] += a;
    }
    __syncthreads();
    if (t < NC) coarse_off[t] = sh[t] - s;
    if (t == 0) { coarse_off[NC] = N_EDGES; offsets[N_NODES] = N_EDGES; }
}

// ---------------- P2: chunked scatter, precomputed bases, LDS-staged write-out ----------------
// pack = src | (dst&1023)<<19
__global__ __launch_bounds__(256)
void p2_scatter(const int* __restrict__ src, const int* __restrict__ dst,
                const int* __restrict__ chunkhist, const int* __restrict__ chunkpre,
                const int* __restrict__ coarse_off, int* __restrict__ bc) {
    __shared__ int lh[NC], wbase[NC], cur[NC];
    __shared__ int sc[512];
    __shared__ int sorted[CHUNK];
    __shared__ unsigned short bkt[CHUNK];
    int t = threadIdx.x, k = blockIdx.x;
    int e0 = k * CHUNK;
    int e1 = min(e0 + CHUNK, N_EDGES);
    int ne = e1 - e0;
    // own hist row + scan -> local layout
    int v0 = (t < NC)       ? chunkhist[(size_t)k * NC + t]       : 0;
    int v1 = (t + 256 < NC) ? chunkhist[(size_t)k * NC + t + 256] : 0;
    sc[t] = v0; sc[t + 256] = v1;
    for (int off = 1; off < 512; off <<= 1) {
        __syncthreads();
        int a = (t >= off) ? sc[t - off] : 0;
        int b = (t + 256 >= off) ? sc[t + 256 - off] : 0;
        __syncthreads();
        sc[t] += a; sc[t + 256] += b;
    }
    __syncthreads();
    if (t < NC) {
        int ex = sc[t] - v0;
        lh[t] = ex; cur[t] = ex;
        wbase[t] = coarse_off[t] + chunkpre[(size_t)k * NC + t] - ex;
    }
    if (t + 256 < NC) {
        int ex = sc[t + 256] - v1;
        lh[t + 256] = ex; cur[t + 256] = ex;
        wbase[t + 256] = coarse_off[t + 256] + chunkpre[(size_t)k * NC + t + 256] - ex;
    }
    __syncthreads();
    // scatter into LDS grouped by bucket
    for (int e = e0 + t; e < e1; e += 256) {
        int d = dst[e];
        int cb = d >> 10;
        int r = atomicAdd(&cur[cb], 1);
        sorted[r] = src[e] | ((d & 1023) << 19);
        bkt[r] = (unsigned short)cb;
    }
    __syncthreads();
    // coalesced-ish write-out: consecutive threads -> consecutive addresses per run
    for (int p = t; p < ne; p += 256) {
        bc[wbase[bkt[p]] + p] = sorted[p];
    }
}

// ---------------- P3: node-exact CSR within each coarse bucket ----------------
__global__ __launch_bounds__(256)
void p3_csr(const int* __restrict__ coarse_off, const int* __restrict__ bc,
            int* __restrict__ offsets, int* __restrict__ csr) {
    int c = blockIdx.x;
    int b0 = coarse_off[c], b1 = coarse_off[c + 1];
    __shared__ int h[1024], cur[1024], ts[256];
    int t = threadIdx.x;
    for (int i = t; i < 1024; i += 256) h[i] = 0;
    __syncthreads();
    for (int i = b0 + t; i < b1; i += 256) atomicAdd(&h[(bc[i] >> 19) & 1023], 1);
    __syncthreads();
    int base4 = t * 4;
    int a0 = h[base4], a1 = h[base4 + 1], a2 = h[base4 + 2], a3 = h[base4 + 3];
    int s = a0 + a1 + a2 + a3;
    ts[t] = s;
    for (int off = 1; off < 256; off <<= 1) {
        __syncthreads();
        int v = (t >= off) ? ts[t - off] : 0;
        __syncthreads();
        ts[t] += v;
    }
    __syncthreads();
    int excl = ts[t] - s;
    h[base4]     = excl;
    h[base4 + 1] = excl + a0;
    h[base4 + 2] = excl + a0 + a1;
    h[base4 + 3] = excl + a0 + a1 + a2;
    cur[base4]     = h[base4];
    cur[base4 + 1] = h[base4 + 1];
    cur[base4 + 2] = h[base4 + 2];
    cur[base4 + 3] = h[base4 + 3];
    __syncthreads();
    int node0 = c << 10;
    for (int i = t; i < 1024; i += 256) {
        int n = node0 + i;
        if (n < N_NODES) offsets[n] = b0 + h[i];
    }
    for (int i = b0 + t; i < b1; i += 256) {
        int v = bc[i];
        int loc = (v >> 19) & 1023;
        int p = atomicAdd(&cur[loc], 1);
        csr[b0 + p] = v & 0x7FFFF;
    }
}

// ---------------- combined weights: wc = w0 @ w1[IN:], db = b0 @ w1[IN:] ----------------
__global__ __launch_bounds__(256)
void weights_kernel(const float* w0_1, const float* b0_1, const float* w1_1,
                    const float* w0_2, const float* b0_2, const float* w1_2,
                    const float* w0_3, const float* b0_3, const float* w1_3,
                    float* __restrict__ out) {
    const float *w0, *b0, *w1; int IN;
    if (blockIdx.x == 0)      { w0 = w0_1; b0 = b0_1; w1 = w1_1; IN = 11; }
    else if (blockIdx.x == 1) { w0 = w0_2; b0 = b0_2; w1 = w1_2; IN = 19; }
    else                      { w0 = w0_3; b0 = b0_3; w1 = w1_3; IN = 19; }
    __shared__ float sw0[19 * 19], sw1b[19 * 19], sb0[19];
    int t = threadIdx.x;
    for (int i = t; i < IN * 19; i += 256) sw0[i]  = w0[i];
    for (int i = t; i < 19 * 19; i += 256) sw1b[i] = w1[IN * 19 + i];
    if (t < 19) sb0[t] = b0[t];
    __syncthreads();
    float* o = out + blockIdx.x * 380;
    for (int idx = t; idx < IN * 19; idx += 256) {
        int i = idx / 19, j = idx - 19 * (idx / 19);
        float s = 0.f;
        #pragma unroll
        for (int k = 0; k < 19; ++k) s = fmaf(sw0[i * 19 + k], sw1b[k * 19 + j], s);
        o[idx] = s;
    }
    if (t < 19) {
        float s = 0.f;
        #pragma unroll
        for (int k = 0; k < 19; ++k) s = fmaf(sb0[k], sw1b[k * 19 + t], s);
        o[361 + t] = s;
    }
}

// ---------------- L1 fused layer: f16 32B-row gather, 8 edge slots x 2 quarters ----------------
__global__ __launch_bounds__(256)
void fused_layer1(const float* __restrict__ x, const char* __restrict__ xg,
                  const int* __restrict__ csr, const int* __restrict__ offsets,
                  const float* __restrict__ w1, const float* __restrict__ b1,
                  const float* __restrict__ wcdb, float* __restrict__ out,
                  char* __restrict__ packout) {
    constexpr int IN = 11;
    __shared__ float sw1a[IN * 19], swc[IN * 19], sdb[19], sb1[19];
    __shared__ float shx[LNPB][IN], shs[LNPB][20];
    __shared__ int   sdeg[LNPB];
    int t = threadIdx.x;
    for (int i = t; i < IN * 19; i += 256) { sw1a[i] = w1[i]; swc[i] = wcdb[i]; }
    if (t < 19) { sdb[t] = wcdb[361 + t]; sb1[t] = b1[t]; }
    int node0 = blockIdx.x * LNPB;
    for (int idx = t; idx < LNPB * IN; idx += 256) {
        int nl = idx / IN, i = idx - nl * IN;
        shx[nl][i] = x[(size_t)(node0 + nl) * IN + i];
    }
    int nl = t >> 4;
    int l16 = t & 15;
    int es = l16 >> 1, k = l16 & 1;     // 8 edge slots x 2 half-rows
    int n = node0 + nl;
    float acc[8] = {0.f, 0.f, 0.f, 0.f, 0.f, 0.f, 0.f, 0.f};
    int o0 = offsets[n], o1 = offsets[n + 1];
    for (int i = o0 + es; i < o1; i += 8) {
        int row = csr[i];
        const float4 v = *(const float4*)(xg + ((size_t)row << 5) + (k << 4));
        const __half2* hp = (const __half2*)&v;
        #pragma unroll
        for (int p = 0; p < 4; ++p) {
            float2 f = __half22float2(hp[p]);
            acc[2 * p]     += f.x;
            acc[2 * p + 1] += f.y;
        }
    }
    #pragma unroll
    for (int j = 0; j < 8; ++j) {
        acc[j] += __shfl_xor(acc[j], 2);
        acc[j] += __shfl_xor(acc[j], 4);
        acc[j] += __shfl_xor(acc[j], 8);
    }
    if (es == 0) {                       // l16 in {0,1}
        #pragma unroll
        for (int j = 0; j < 8; ++j) shs[nl][8 * k + j] = acc[j];   // ch 0..15 (11..15 ignored)
        if (k == 0) sdeg[nl] = o1 - o0;
    }
    __syncthreads();
    for (int idx = t; idx < LNPB * 19; idx += 256) {
        int nl2 = idx / 19, cc = idx - nl2 * 19;
        int n2 = node0 + nl2;
        float v = sb1[cc] + (float)sdeg[nl2] * sdb[cc];
        #pragma unroll
        for (int i = 0; i < IN; ++i) v = fmaf(shx[nl2][i], sw1a[i * 19 + cc], v);
        #pragma unroll
        for (int i = 0; i < IN; ++i) v = fmaf(shs[nl2][i], swc[i * 19 + cc], v);
        v = fmaxf(v, 0.f);
        out[(size_t)n2 * 19 + cc] = v;
        char* prow = packout + ((size_t)n2 << 6);
        if (cc < 13) *(float*)(prow + 4 * cc) = v;
        else         *(__half*)(prow + 52 + 2 * (cc - 13)) = __float2half(v);
    }
}

// ---------------- layers 2/3: 64B packed-row gather (13 f32 + 6 f16) ----------------
template<bool WPACK>
__global__ __launch_bounds__(256)
void fused_layer(const float* __restrict__ x, const char* __restrict__ xg,
                 const int* __restrict__ csr, const int* __restrict__ offsets,
                 const float* __restrict__ w1, const float* __restrict__ b1,
                 const float* __restrict__ wcdb, float* __restrict__ out,
                 char* __restrict__ packout) {
    constexpr int IN = 19;
    __shared__ float sw1a[IN * 19], swc[IN * 19], sdb[19], sb1[19];
    __shared__ float shx[LNPB][19], shs[LNPB][20];
    __shared__ int   sdeg[LNPB];
    int t = threadIdx.x;
    for (int i = t; i < IN * 19; i += 256) { sw1a[i] = w1[i]; swc[i] = wcdb[i]; }
    if (t < 19) { sdb[t] = wcdb[361 + t]; sb1[t] = b1[t]; }
    int node0 = blockIdx.x * LNPB;
    for (int idx = t; idx < LNPB * IN; idx += 256) {
        int nl = idx / IN, i = idx - nl * IN;
        shx[nl][i] = x[(size_t)(node0 + nl) * IN + i];
    }
    int nl = t >> 4;
    int l16 = t & 15;
    int es = l16 >> 2, k = l16 & 3;
    int n = node0 + nl;
    float acc[8] = {0.f, 0.f, 0.f, 0.f, 0.f, 0.f, 0.f, 0.f};
    int o0 = offsets[n], o1 = offsets[n + 1];
    for (int i = o0 + es; i < o1; i += 4) {
        int row = csr[i];
        const float4 v = *(const float4*)(xg + ((size_t)row << 6) + (k << 4));
        if (k == 3) {
            acc[0] += v.x;                          // ch12 (f32)
            const __half2* hp = (const __half2*)&v.y;
            float2 a = __half22float2(hp[0]);
            float2 b = __half22float2(hp[1]);
            float2 c = __half22float2(hp[2]);
            acc[1] += a.x; acc[2] += a.y;
            acc[3] += b.x; acc[4] += b.y;
            acc[5] += c.x; acc[6] += c.y;
        } else {
            acc[0] += v.x; acc[1] += v.y; acc[2] += v.z; acc[3] += v.w;
        }
    }
    #pragma unroll
    for (int j = 0; j < 8; ++j) {
        acc[j] += __shfl_xor(acc[j], 4);
        acc[j] += __shfl_xor(acc[j], 8);
    }
    if (es == 0) {
        if (k == 3) {
            shs[nl][12] = acc[0];
            #pragma unroll
            for (int j = 0; j < 6; ++j) shs[nl][13 + j] = acc[1 + j];
        } else {
            #pragma unroll
            for (int j = 0; j < 4; ++j) {
                int ch = 4 * k + j;
                if (ch < 19) shs[nl][ch] = acc[j];
            }
        }
        if (k == 0) sdeg[nl] = o1 - o0;
    }
    __syncthreads();
    for (int idx = t; idx < LNPB * 19; idx += 256) {
        int nl2 = idx / 19, cc = idx - nl2 * 19;
        int n2 = node0 + nl2;
        float v = sb1[cc] + (float)sdeg[nl2] * sdb[cc];
        #pragma unroll
        for (int i = 0; i < IN; ++i) v = fmaf(shx[nl2][i], sw1a[i * 19 + cc], v);
        #pragma unroll
        for (int i = 0; i < IN; ++i) v = fmaf(shs[nl2][i], swc[i * 19 + cc], v);
        v += shx[nl2][cc];               // residual (layers 2/3 always)
        v = fmaxf(v, 0.f);
        out[(size_t)n2 * 19 + cc] = v;
        if (WPACK) {
            char* prow = packout + ((size_t)n2 << 6);
            if (cc < 13) *(float*)(prow + 4 * cc) = v;
            else         *(__half*)(prow + 52 + 2 * (cc - 13)) = __float2half(v);
        }
    }
}

// ---------------- readout ----------------
__global__ __launch_bounds__(256)
void readout_kernel(const float* __restrict__ h, const int* __restrict__ pos,
                    const float* __restrict__ w0, const float* __restrict__ b0,
                    const float* __restrict__ w1, const float* __restrict__ b1,
                    float* __restrict__ out) {
    __shared__ float ws[HID * 10 + 10 + 10 + 1];
    for (int i = threadIdx.x; i < 211; i += 256) {
        float v;
        if (i < 190)      v = w0[i];
        else if (i < 200) v = b0[i - 190];
        else if (i < 210) v = w1[i - 200];
        else              v = b1[0];
        ws[i] = v;
    }
    __syncthreads();
    int g = blockIdx.x * 256 + threadIdx.x;
    if (g >= N_GRAPHS) return;
    const float* hp = h + (size_t)pos[g] * HID;
    float t[10];
    #pragma unroll
    for (int j = 0; j < 10; ++j) {
        float acc = ws[190 + j];
        #pragma unroll
        for (int i = 0; i < HID; ++i) acc = fmaf(hp[i], ws[i * 10 + j], acc);
        t[j] = fmaxf(acc, 0.0f);
    }
    float o = ws[210];
    #pragma unroll
    for (int j = 0; j < 10; ++j) o = fmaf(t[j], ws[200 + j], o);
    out[g] = fmaxf(o, 0.0f);
}

extern "C" void kernel_launch(void* const* d_in, const int* in_sizes, int n_in,
                              void* d_out, int out_size, void* d_ws, size_t ws_size,
                              hipStream_t stream) {
    const float* x     = (const float*)d_in[0];
    const int*   ei    = (const int*)d_in[1];
    const int*   batch = (const int*)d_in[2];
    const float* w0_1 = (const float*)d_in[3];
    const float* b0_1 = (const float*)d_in[4];
    const float* w1_1 = (const float*)d_in[5];
    const float* b1_1 = (const float*)d_in[6];
    const float* w0_2 = (const float*)d_in[7];
    const float* b0_2 = (const float*)d_in[8];
    const float* w1_2 = (const float*)d_in[9];
    const float* b1_2 = (const float*)d_in[10];
    const float* w0_3 = (const float*)d_in[11];
    const float* b0_3 = (const float*)d_in[12];
    const float* w1_3 = (const float*)d_in[13];
    const float* b1_3 = (const float*)d_in[14];
    const float* wfc0 = (const float*)d_in[15];
    const float* bfc0 = (const float*)d_in[16];
    const float* wfc1 = (const float*)d_in[17];
    const float* bfc1 = (const float*)d_in[18];

    const int* src = ei;            // edge_index[0]
    const int* dst = ei + N_EDGES;  // edge_index[1]

    char* ws = (char*)d_ws;
    size_t off = 0;
    auto alloc = [&](size_t bytes) { void* p = ws + off; off = (off + bytes + 511) & ~(size_t)511; return p; };
    float* BUF_A     = (float*)alloc((size_t)N_NODES * HID * 4);   // 38 MB (L1 out, L3 out)
    float* BUF_C     = (float*)alloc((size_t)N_NODES * HID * 4);   // 38 MB (L2 out)
    char*  SCRATCH   = (char*) alloc((size_t)N_EDGES * 4);         // 32 MB: bc (sort), later PACK2
    char*  XP        = (char*) alloc((size_t)N_NODES * 32);        // 16 MB: L1 f16 gather rows
    char*  PACK1     = (char*) alloc((size_t)N_NODES * 64);        // 32 MB: L1 -> L2 packed rows
    int*   csr       = (int*)  alloc((size_t)N_EDGES * 4);         // 32 MB
    int*   offsets   = (int*)  alloc(((size_t)N_NODES + 1) * 4);
    int*   chunkhist = (int*)  alloc((size_t)P2B * NC * 4);        // 1.9 MB
    int*   chunkpre  = (int*)  alloc((size_t)P2B * NC * 4);        // 1.9 MB
    int*   coarse_off= (int*)  alloc((NC + 1) * 4);
    int*   coltotal  = (int*)  alloc(NC * 4);
    int*   pos       = (int*)  alloc((size_t)N_GRAPHS * 4);
    float* wcdb      = (float*)alloc(3 * 380 * 4);
    int*   bc        = (int*)SCRATCH;
    char*  PACK2     = SCRATCH;     // bc dead after p3; written by L2, read by L3

    dim3 blk(256);
    int gridN = (N_NODES + 255) / 256;
    int gridL = N_NODES / LNPB;              // 31250, exact
    int gridG = (N_GRAPHS + 255) / 256;

    weights_kernel<<<3, blk, 0, stream>>>(w0_1, b0_1, w1_1, w0_2, b0_2, w1_2,
                                          w0_3, b0_3, w1_3, wcdb);
    prep_kernel<<<gridN, blk, 0, stream>>>(x, (__half*)XP, batch, pos);

    // ---- bucket sort -> node-exact CSR (deterministic bases, no global atomics) ----
    p1_hist<<<P2B, blk, 0, stream>>>(dst, chunkhist);
    ka_chunkscan<<<NC, blk, 0, stream>>>(chunkhist, chunkpre, coltotal);
    kb_scan<<<1, 512, 0, stream>>>(coltotal, coarse_off, offsets);
    p2_scatter<<<P2B, blk, 0, stream>>>(src, dst, chunkhist, chunkpre, coarse_off, bc);
    p3_csr<<<NC, blk, 0, stream>>>(coarse_off, bc, offsets, csr);

    // ---- 3 fused layers ----
    // L1: self x (11ch f32), gather XP (32B f16 rows) -> BUF_A + PACK1
    fused_layer1<<<gridL, blk, 0, stream>>>(
        x, XP, csr, offsets, w1_1, b1_1, wcdb, BUF_A, PACK1);
    // L2: self BUF_A, gather PACK1 -> BUF_C + PACK2
    fused_layer<true ><<<gridL, blk, 0, stream>>>(
        BUF_A, PACK1, csr, offsets, w1_2, b1_2, wcdb + 380, BUF_C, PACK2);
    // L3: self BUF_C, gather PACK2 -> BUF_A
    fused_layer<false><<<gridL, blk, 0, stream>>>(
        BUF_C, PACK2, csr, offsets, w1_3, b1_3, wcdb + 760, BUF_A, nullptr);

    // ---- Readout ----
    readout_kernel<<<gridG, blk, 0, stream>>>(BUF_A, pos, wfc0, bfc0, wfc1, bfc1,
                                              (float*)d_out);
}

// Round 10
// 629.547 us; speedup vs baseline: 1.6090x; 1.0617x over previous
//
#include <hip/hip_runtime.h>
#include <hip/hip_fp16.h>

constexpr int N_NODES  = 500000;
constexpr int N_EDGES  = 8000000;
constexpr int N_GRAPHS = 25000;
constexpr int HID      = 19;

constexpr int NC    = (N_NODES + 1023) / 1024;   // 489 coarse buckets (dst>>10)
constexpr int CHUNK = 8192;                      // edges per sort chunk
constexpr int P2B   = (N_EDGES + CHUNK - 1) / CHUNK;  // 977 chunks
constexpr int LNPB  = 16;                        // nodes per 256-thread layer block

// ---------------- prep: x (11ch f32) -> xp rows (32B: 11 f16 + pad) + pos ----------------
__global__ __launch_bounds__(256)
void prep_kernel(const float* __restrict__ x, __half* __restrict__ xp,
                 const int* __restrict__ batch, int* __restrict__ pos) {
    int i = blockIdx.x * 256 + threadIdx.x;
    if (i >= N_NODES) return;
    int b  = batch[i];
    int nb = (i == N_NODES - 1) ? N_GRAPHS : batch[i + 1];
    for (int g = b; g < nb; ++g) pos[g] = i;
    if (i == 0) {
        for (int g = 0; g < b; ++g) pos[g] = N_NODES - 1;   // JAX -1 wrap
    }
    const float* xs = x + (size_t)i * 11;
    __half* xd = xp + (size_t)i * 16;
    #pragma unroll
    for (int k = 0; k < 11; ++k) xd[k] = __float2half(xs[k]);
    #pragma unroll
    for (int k = 11; k < 16; ++k) xd[k] = __half(0.0f);
}

// ---------------- P1: per-chunk coarse histograms ----------------
__global__ __launch_bounds__(256)
void p1_hist(const int* __restrict__ dst, int* __restrict__ chunkhist) {
    __shared__ int h[NC];
    int t = threadIdx.x, k = blockIdx.x;
    for (int i = t; i < NC; i += 256) h[i] = 0;
    __syncthreads();
    int e0 = k * CHUNK;
    int e1 = min(e0 + CHUNK, N_EDGES);
    for (int e = e0 + t; e < e1; e += 256) atomicAdd(&h[dst[e] >> 10], 1);
    __syncthreads();
    for (int i = t; i < NC; i += 256) chunkhist[(size_t)k * NC + i] = h[i];
}

// ---------------- KA: per-bucket exclusive scan across chunks ----------------
__global__ __launch_bounds__(256)
void ka_chunkscan(const int* __restrict__ chunkhist, int* __restrict__ chunkpre,
                  int* __restrict__ coltotal) {
    int c = blockIdx.x, t = threadIdx.x;
    int v[4];
    #pragma unroll
    for (int j = 0; j < 4; ++j) {
        int k = 4 * t + j;
        v[j] = (k < P2B) ? chunkhist[(size_t)k * NC + c] : 0;
    }
    int s = v[0] + v[1] + v[2] + v[3];
    __shared__ int sc[256];
    sc[t] = s;
    for (int off = 1; off < 256; off <<= 1) {
        __syncthreads();
        int a = (t >= off) ? sc[t - off] : 0;
        __syncthreads();
        sc[t] += a;
    }
    __syncthreads();
    int run = sc[t] - s;   // exclusive over threads
    #pragma unroll
    for (int j = 0; j < 4; ++j) {
        int k = 4 * t + j;
        if (k < P2B) chunkpre[(size_t)k * NC + c] = run;
        run += v[j];
    }
    if (t == 255) coltotal[c] = run;
}

// ---------------- KB: scan bucket totals -> coarse_off ----------------
__global__ __launch_bounds__(512)
void kb_scan(const int* __restrict__ coltotal, int* __restrict__ coarse_off,
             int* __restrict__ offsets) {
    __shared__ int sh[512];
    int t = threadIdx.x;
    int s = (t < NC) ? coltotal[t] : 0;
    sh[t] = s;
    for (int off = 1; off < 512; off <<= 1) {
        __syncthreads();
        int a = (t >= off) ? sh[t - off] : 0;
        __syncthreads();
        sh[t] += a;
    }
    __syncthreads();
    if (t < NC) coarse_off[t] = sh[t] - s;
    if (t == 0) { coarse_off[NC] = N_EDGES; offsets[N_NODES] = N_EDGES; }
}

// ---------------- P2: chunked scatter, precomputed bases, LDS-staged write-out ----------------
// pack = src | (dst&1023)<<19
__global__ __launch_bounds__(256)
void p2_scatter(const int* __restrict__ src, const int* __restrict__ dst,
                const int* __restrict__ chunkhist, const int* __restrict__ chunkpre,
                const int* __restrict__ coarse_off, int* __restrict__ bc) {
    __shared__ int wbase[NC], cur[NC];
    __shared__ int sc[512];
    __shared__ int sorted[CHUNK];
    __shared__ unsigned short bkt[CHUNK];
    int t = threadIdx.x, k = blockIdx.x;
    int e0 = k * CHUNK;
    int e1 = min(e0 + CHUNK, N_EDGES);
    int ne = e1 - e0;
    // own hist row + scan -> local layout
    int v0 = (t < NC)       ? chunkhist[(size_t)k * NC + t]       : 0;
    int v1 = (t + 256 < NC) ? chunkhist[(size_t)k * NC + t + 256] : 0;
    sc[t] = v0; sc[t + 256] = v1;
    for (int off = 1; off < 512; off <<= 1) {
        __syncthreads();
        int a = (t >= off) ? sc[t - off] : 0;
        int b = (t + 256 >= off) ? sc[t + 256 - off] : 0;
        __syncthreads();
        sc[t] += a; sc[t + 256] += b;
    }
    __syncthreads();
    if (t < NC) {
        int ex = sc[t] - v0;
        cur[t] = ex;
        wbase[t] = coarse_off[t] + chunkpre[(size_t)k * NC + t] - ex;
    }
    if (t + 256 < NC) {
        int ex = sc[t + 256] - v1;
        cur[t + 256] = ex;
        wbase[t + 256] = coarse_off[t + 256] + chunkpre[(size_t)k * NC + t + 256] - ex;
    }
    __syncthreads();
    // scatter into LDS grouped by bucket
    for (int e = e0 + t; e < e1; e += 256) {
        int d = dst[e];
        int cb = d >> 10;
        int r = atomicAdd(&cur[cb], 1);
        sorted[r] = src[e] | ((d & 1023) << 19);
        bkt[r] = (unsigned short)cb;
    }
    __syncthreads();
    // coalesced-ish write-out: consecutive threads -> consecutive addresses per run
    for (int p = t; p < ne; p += 256) {
        bc[wbase[bkt[p]] + p] = sorted[p];
    }
}

// ---------------- P3: node-exact CSR within each coarse bucket ----------------
__global__ __launch_bounds__(256)
void p3_csr(const int* __restrict__ coarse_off, const int* __restrict__ bc,
            int* __restrict__ offsets, int* __restrict__ csr) {
    int c = blockIdx.x;
    int b0 = coarse_off[c], b1 = coarse_off[c + 1];
    __shared__ int h[1024], cur[1024], ts[256];
    int t = threadIdx.x;
    for (int i = t; i < 1024; i += 256) h[i] = 0;
    __syncthreads();
    for (int i = b0 + t; i < b1; i += 256) atomicAdd(&h[(bc[i] >> 19) & 1023], 1);
    __syncthreads();
    int base4 = t * 4;
    int a0 = h[base4], a1 = h[base4 + 1], a2 = h[base4 + 2], a3 = h[base4 + 3];
    int s = a0 + a1 + a2 + a3;
    ts[t] = s;
    for (int off = 1; off < 256; off <<= 1) {
        __syncthreads();
        int v = (t >= off) ? ts[t - off] : 0;
        __syncthreads();
        ts[t] += v;
    }
    __syncthreads();
    int excl = ts[t] - s;
    h[base4]     = excl;
    h[base4 + 1] = excl + a0;
    h[base4 + 2] = excl + a0 + a1;
    h[base4 + 3] = excl + a0 + a1 + a2;
    cur[base4]     = h[base4];
    cur[base4 + 1] = h[base4 + 1];
    cur[base4 + 2] = h[base4 + 2];
    cur[base4 + 3] = h[base4 + 3];
    __syncthreads();
    int node0 = c << 10;
    for (int i = t; i < 1024; i += 256) {
        int n = node0 + i;
        if (n < N_NODES) offsets[n] = b0 + h[i];
    }
    for (int i = b0 + t; i < b1; i += 256) {
        int v = bc[i];
        int loc = (v >> 19) & 1023;
        int p = atomicAdd(&cur[loc], 1);
        csr[b0 + p] = v & 0x7FFFF;
    }
}

// ---------------- combined weights: wc = w0 @ w1[IN:], db = b0 @ w1[IN:] ----------------
__global__ __launch_bounds__(256)
void weights_kernel(const float* w0_1, const float* b0_1, const float* w1_1,
                    const float* w0_2, const float* b0_2, const float* w1_2,
                    const float* w0_3, const float* b0_3, const float* w1_3,
                    float* __restrict__ out) {
    const float *w0, *b0, *w1; int IN;
    if (blockIdx.x == 0)      { w0 = w0_1; b0 = b0_1; w1 = w1_1; IN = 11; }
    else if (blockIdx.x == 1) { w0 = w0_2; b0 = b0_2; w1 = w1_2; IN = 19; }
    else                      { w0 = w0_3; b0 = b0_3; w1 = w1_3; IN = 19; }
    __shared__ float sw0[19 * 19], sw1b[19 * 19], sb0[19];
    int t = threadIdx.x;
    for (int i = t; i < IN * 19; i += 256) sw0[i]  = w0[i];
    for (int i = t; i < 19 * 19; i += 256) sw1b[i] = w1[IN * 19 + i];
    if (t < 19) sb0[t] = b0[t];
    __syncthreads();
    float* o = out + blockIdx.x * 380;
    for (int idx = t; idx < IN * 19; idx += 256) {
        int i = idx / 19, j = idx - 19 * (idx / 19);
        float s = 0.f;
        #pragma unroll
        for (int k = 0; k < 19; ++k) s = fmaf(sw0[i * 19 + k], sw1b[k * 19 + j], s);
        o[idx] = s;
    }
    if (t < 19) {
        float s = 0.f;
        #pragma unroll
        for (int k = 0; k < 19; ++k) s = fmaf(sb0[k], sw1b[k * 19 + t], s);
        o[361 + t] = s;
    }
}

// ---------------- L1 fused layer: f16 32B-row gather -> packed 64B out only ----------------
__global__ __launch_bounds__(256)
void fused_layer1(const float* __restrict__ x, const char* __restrict__ xg,
                  const int* __restrict__ csr, const int* __restrict__ offsets,
                  const float* __restrict__ w1, const float* __restrict__ b1,
                  const float* __restrict__ wcdb, char* __restrict__ packout) {
    constexpr int IN = 11;
    __shared__ float sw1a[IN * 19], swc[IN * 19], sdb[19], sb1[19];
    __shared__ float shx[LNPB][IN], shs[LNPB][20];
    __shared__ int   sdeg[LNPB];
    int t = threadIdx.x;
    for (int i = t; i < IN * 19; i += 256) { sw1a[i] = w1[i]; swc[i] = wcdb[i]; }
    if (t < 19) { sdb[t] = wcdb[361 + t]; sb1[t] = b1[t]; }
    int node0 = blockIdx.x * LNPB;
    for (int idx = t; idx < LNPB * IN; idx += 256) {
        int nl = idx / IN, i = idx - nl * IN;
        shx[nl][i] = x[(size_t)(node0 + nl) * IN + i];
    }
    int nl = t >> 4;
    int l16 = t & 15;
    int es = l16 >> 1, k = l16 & 1;     // 8 edge slots x 2 half-rows
    int n = node0 + nl;
    float acc[8] = {0.f, 0.f, 0.f, 0.f, 0.f, 0.f, 0.f, 0.f};
    int o0 = offsets[n], o1 = offsets[n + 1];
    for (int i = o0 + es; i < o1; i += 8) {
        int row = csr[i];
        const float4 v = *(const float4*)(xg + ((size_t)row << 5) + (k << 4));
        const __half2* hp = (const __half2*)&v;
        #pragma unroll
        for (int p = 0; p < 4; ++p) {
            float2 f = __half22float2(hp[p]);
            acc[2 * p]     += f.x;
            acc[2 * p + 1] += f.y;
        }
    }
    #pragma unroll
    for (int j = 0; j < 8; ++j) {
        acc[j] += __shfl_xor(acc[j], 2);
        acc[j] += __shfl_xor(acc[j], 4);
        acc[j] += __shfl_xor(acc[j], 8);
    }
    if (es == 0) {                       // l16 in {0,1}
        #pragma unroll
        for (int j = 0; j < 8; ++j) shs[nl][8 * k + j] = acc[j];   // ch 0..15 (11..15 ignored)
        if (k == 0) sdeg[nl] = o1 - o0;
    }
    __syncthreads();
    for (int idx = t; idx < LNPB * 19; idx += 256) {
        int nl2 = idx / 19, cc = idx - nl2 * 19;
        int n2 = node0 + nl2;
        float v = sb1[cc] + (float)sdeg[nl2] * sdb[cc];
        #pragma unroll
        for (int i = 0; i < IN; ++i) v = fmaf(shx[nl2][i], sw1a[i * 19 + cc], v);
        #pragma unroll
        for (int i = 0; i < IN; ++i) v = fmaf(shs[nl2][i], swc[i * 19 + cc], v);
        v = fmaxf(v, 0.f);
        char* prow = packout + ((size_t)n2 << 6);
        if (cc < 13) *(float*)(prow + 4 * cc) = v;
        else         *(__half*)(prow + 52 + 2 * (cc - 13)) = __float2half(v);
    }
}

// ---------------- layers 2/3: packed-row self + gather (13 f32 + 6 f16), packed out ----------------
__global__ __launch_bounds__(256)
void fused_layer23(const char* __restrict__ xself, const char* __restrict__ xg,
                   const int* __restrict__ csr, const int* __restrict__ offsets,
                   const float* __restrict__ w1, const float* __restrict__ b1,
                   const float* __restrict__ wcdb, char* __restrict__ packout) {
    constexpr int IN = 19;
    __shared__ float sw1a[IN * 19], swc[IN * 19], sdb[19], sb1[19];
    __shared__ float shx[LNPB][19], shs[LNPB][20];
    __shared__ int   sdeg[LNPB];
    int t = threadIdx.x;
    for (int i = t; i < IN * 19; i += 256) { sw1a[i] = w1[i]; swc[i] = wcdb[i]; }
    if (t < 19) { sdb[t] = wcdb[361 + t]; sb1[t] = b1[t]; }
    int node0 = blockIdx.x * LNPB;
    // self rows from packed buffer (streaming, L2-friendly)
    for (int idx = t; idx < LNPB * 19; idx += 256) {
        int nl = idx / 19, cc = idx - nl * 19;
        const char* prow = xself + ((size_t)(node0 + nl) << 6);
        shx[nl][cc] = (cc < 13) ? *(const float*)(prow + 4 * cc)
                                : __half2float(*(const __half*)(prow + 52 + 2 * (cc - 13)));
    }
    int nl = t >> 4;
    int l16 = t & 15;
    int es = l16 >> 2, k = l16 & 3;
    int n = node0 + nl;
    float acc[8] = {0.f, 0.f, 0.f, 0.f, 0.f, 0.f, 0.f, 0.f};
    int o0 = offsets[n], o1 = offsets[n + 1];
    for (int i = o0 + es; i < o1; i += 4) {
        int row = csr[i];
        const float4 v = *(const float4*)(xg + ((size_t)row << 6) + (k << 4));
        if (k == 3) {
            acc[0] += v.x;                          // ch12 (f32)
            const __half2* hp = (const __half2*)&v.y;
            float2 a = __half22float2(hp[0]);
            float2 b = __half22float2(hp[1]);
            float2 c = __half22float2(hp[2]);
            acc[1] += a.x; acc[2] += a.y;
            acc[3] += b.x; acc[4] += b.y;
            acc[5] += c.x; acc[6] += c.y;
        } else {
            acc[0] += v.x; acc[1] += v.y; acc[2] += v.z; acc[3] += v.w;
        }
    }
    #pragma unroll
    for (int j = 0; j < 8; ++j) {
        acc[j] += __shfl_xor(acc[j], 4);
        acc[j] += __shfl_xor(acc[j], 8);
    }
    if (es == 0) {
        if (k == 3) {
            shs[nl][12] = acc[0];
            #pragma unroll
            for (int j = 0; j < 6; ++j) shs[nl][13 + j] = acc[1 + j];
        } else {
            #pragma unroll
            for (int j = 0; j < 4; ++j) {
                int ch = 4 * k + j;
                if (ch < 19) shs[nl][ch] = acc[j];
            }
        }
        if (k == 0) sdeg[nl] = o1 - o0;
    }
    __syncthreads();
    for (int idx = t; idx < LNPB * 19; idx += 256) {
        int nl2 = idx / 19, cc = idx - nl2 * 19;
        int n2 = node0 + nl2;
        float v = sb1[cc] + (float)sdeg[nl2] * sdb[cc];
        #pragma unroll
        for (int i = 0; i < IN; ++i) v = fmaf(shx[nl2][i], sw1a[i * 19 + cc], v);
        #pragma unroll
        for (int i = 0; i < IN; ++i) v = fmaf(shs[nl2][i], swc[i * 19 + cc], v);
        v += shx[nl2][cc];               // residual
        v = fmaxf(v, 0.f);
        char* prow = packout + ((size_t)n2 << 6);
        if (cc < 13) *(float*)(prow + 4 * cc) = v;
        else         *(__half*)(prow + 52 + 2 * (cc - 13)) = __float2half(v);
    }
}

// ---------------- readout (packed input rows) ----------------
__global__ __launch_bounds__(256)
void readout_kernel(const char* __restrict__ pack, const int* __restrict__ pos,
                    const float* __restrict__ w0, const float* __restrict__ b0,
                    const float* __restrict__ w1, const float* __restrict__ b1,
                    float* __restrict__ out) {
    __shared__ float ws[HID * 10 + 10 + 10 + 1];
    for (int i = threadIdx.x; i < 211; i += 256) {
        float v;
        if (i < 190)      v = w0[i];
        else if (i < 200) v = b0[i - 190];
        else if (i < 210) v = w1[i - 200];
        else              v = b1[0];
        ws[i] = v;
    }
    __syncthreads();
    int g = blockIdx.x * 256 + threadIdx.x;
    if (g >= N_GRAPHS) return;
    const char* prow = pack + ((size_t)pos[g] << 6);
    float hv[19];
    #pragma unroll
    for (int i = 0; i < 13; ++i) hv[i] = *(const float*)(prow + 4 * i);
    #pragma unroll
    for (int i = 13; i < 19; ++i) hv[i] = __half2float(*(const __half*)(prow + 52 + 2 * (i - 13)));
    float t[10];
    #pragma unroll
    for (int j = 0; j < 10; ++j) {
        float acc = ws[190 + j];
        #pragma unroll
        for (int i = 0; i < HID; ++i) acc = fmaf(hv[i], ws[i * 10 + j], acc);
        t[j] = fmaxf(acc, 0.0f);
    }
    float o = ws[210];
    #pragma unroll
    for (int j = 0; j < 10; ++j) o = fmaf(t[j], ws[200 + j], o);
    out[g] = fmaxf(o, 0.0f);
}

extern "C" void kernel_launch(void* const* d_in, const int* in_sizes, int n_in,
                              void* d_out, int out_size, void* d_ws, size_t ws_size,
                              hipStream_t stream) {
    const float* x     = (const float*)d_in[0];
    const int*   ei    = (const int*)d_in[1];
    const int*   batch = (const int*)d_in[2];
    const float* w0_1 = (const float*)d_in[3];
    const float* b0_1 = (const float*)d_in[4];
    const float* w1_1 = (const float*)d_in[5];
    const float* b1_1 = (const float*)d_in[6];
    const float* w0_2 = (const float*)d_in[7];
    const float* b0_2 = (const float*)d_in[8];
    const float* w1_2 = (const float*)d_in[9];
    const float* b1_2 = (const float*)d_in[10];
    const float* w0_3 = (const float*)d_in[11];
    const float* b0_3 = (const float*)d_in[12];
    const float* w1_3 = (const float*)d_in[13];
    const float* b1_3 = (const float*)d_in[14];
    const float* wfc0 = (const float*)d_in[15];
    const float* bfc0 = (const float*)d_in[16];
    const float* wfc1 = (const float*)d_in[17];
    const float* bfc1 = (const float*)d_in[18];

    const int* src = ei;            // edge_index[0]
    const int* dst = ei + N_EDGES;  // edge_index[1]

    char* ws = (char*)d_ws;
    size_t off = 0;
    auto alloc = [&](size_t bytes) { void* p = ws + off; off = (off + bytes + 511) & ~(size_t)511; return p; };
    char*  SCRATCH   = (char*) alloc((size_t)N_EDGES * 4);         // 32 MB: bc (sort), later PACK2
    char*  PACK1     = (char*) alloc((size_t)N_NODES * 64);        // 32 MB: L1 out / L2 gather; later L3 out
    char*  XP        = (char*) alloc((size_t)N_NODES * 32);        // 16 MB: L1 f16 gather rows
    int*   csr       = (int*)  alloc((size_t)N_EDGES * 4);         // 32 MB
    int*   offsets   = (int*)  alloc(((size_t)N_NODES + 1) * 4);
    int*   chunkhist = (int*)  alloc((size_t)P2B * NC * 4);        // 1.9 MB
    int*   chunkpre  = (int*)  alloc((size_t)P2B * NC * 4);        // 1.9 MB
    int*   coarse_off= (int*)  alloc((NC + 1) * 4);
    int*   coltotal  = (int*)  alloc(NC * 4);
    int*   pos       = (int*)  alloc((size_t)N_GRAPHS * 4);
    float* wcdb      = (float*)alloc(3 * 380 * 4);
    int*   bc        = (int*)SCRATCH;
    char*  PACK2     = SCRATCH;     // bc dead after p3; L2 out / L3 gather+self
    char*  PACK3     = PACK1;       // PACK1 content dead after L2 -> L3 out

    dim3 blk(256);
    int gridN = (N_NODES + 255) / 256;
    int gridL = N_NODES / LNPB;              // 31250, exact
    int gridG = (N_GRAPHS + 255) / 256;

    weights_kernel<<<3, blk, 0, stream>>>(w0_1, b0_1, w1_1, w0_2, b0_2, w1_2,
                                          w0_3, b0_3, w1_3, wcdb);
    prep_kernel<<<gridN, blk, 0, stream>>>(x, (__half*)XP, batch, pos);

    // ---- bucket sort -> node-exact CSR (deterministic bases, no global atomics) ----
    p1_hist<<<P2B, blk, 0, stream>>>(dst, chunkhist);
    ka_chunkscan<<<NC, blk, 0, stream>>>(chunkhist, chunkpre, coltotal);
    kb_scan<<<1, 512, 0, stream>>>(coltotal, coarse_off, offsets);
    p2_scatter<<<P2B, blk, 0, stream>>>(src, dst, chunkhist, chunkpre, coarse_off, bc);
    p3_csr<<<NC, blk, 0, stream>>>(coarse_off, bc, offsets, csr);

    // ---- 3 fused layers, packed 64B inter-layer rows ----
    fused_layer1<<<gridL, blk, 0, stream>>>(
        x, XP, csr, offsets, w1_1, b1_1, wcdb, PACK1);
    fused_layer23<<<gridL, blk, 0, stream>>>(
        PACK1, PACK1, csr, offsets, w1_2, b1_2, wcdb + 380, PACK2);
    fused_layer23<<<gridL, blk, 0, stream>>>(
        PACK2, PACK2, csr, offsets, w1_3, b1_3, wcdb + 760, PACK3);

    // ---- Readout ----
    readout_kernel<<<gridG, blk, 0, stream>>>(PACK3, pos, wfc0, bfc0, wfc1, bfc1,
                                              (float*)d_out);
}

// Round 11
// 602.273 us; speedup vs baseline: 1.6819x; 1.0453x over previous
//
#include <hip/hip_runtime.h>
#include <hip/hip_fp16.h>

constexpr int N_NODES  = 500000;
constexpr int N_EDGES  = 8000000;
constexpr int N_GRAPHS = 25000;
constexpr int HID      = 19;

constexpr int NC    = (N_NODES + 1023) / 1024;   // 489 coarse buckets (dst>>10)
constexpr int CHUNK = 8192;                      // edges per sort chunk
constexpr int P2B   = (N_EDGES + CHUNK - 1) / CHUNK;  // 977 chunks
constexpr int LNPB  = 16;                        // nodes per 256-thread L2/L3 block
constexpr int L1NPB = 32;                        // nodes per 256-thread L1 block (8 lanes/node)

// ---------------- prep: x (11ch f32) -> xp rows (32B: 11 f16 + pad) + pos ----------------
__global__ __launch_bounds__(256)
void prep_kernel(const float* __restrict__ x, __half* __restrict__ xp,
                 const int* __restrict__ batch, int* __restrict__ pos) {
    int i = blockIdx.x * 256 + threadIdx.x;
    if (i >= N_NODES) return;
    int b  = batch[i];
    int nb = (i == N_NODES - 1) ? N_GRAPHS : batch[i + 1];
    for (int g = b; g < nb; ++g) pos[g] = i;
    if (i == 0) {
        for (int g = 0; g < b; ++g) pos[g] = N_NODES - 1;   // JAX -1 wrap
    }
    const float* xs = x + (size_t)i * 11;
    __half* xd = xp + (size_t)i * 16;
    #pragma unroll
    for (int k = 0; k < 11; ++k) xd[k] = __float2half(xs[k]);
    #pragma unroll
    for (int k = 11; k < 16; ++k) xd[k] = __half(0.0f);
}

// ---------------- P1: per-chunk coarse histograms ----------------
__global__ __launch_bounds__(256)
void p1_hist(const int* __restrict__ dst, int* __restrict__ chunkhist) {
    __shared__ int h[NC];
    int t = threadIdx.x, k = blockIdx.x;
    for (int i = t; i < NC; i += 256) h[i] = 0;
    __syncthreads();
    int e0 = k * CHUNK;
    int e1 = min(e0 + CHUNK, N_EDGES);
    for (int e = e0 + t; e < e1; e += 256) atomicAdd(&h[dst[e] >> 10], 1);
    __syncthreads();
    for (int i = t; i < NC; i += 256) chunkhist[(size_t)k * NC + i] = h[i];
}

// ---------------- KA: per-bucket exclusive scan across chunks ----------------
__global__ __launch_bounds__(256)
void ka_chunkscan(const int* __restrict__ chunkhist, int* __restrict__ chunkpre,
                  int* __restrict__ coltotal) {
    int c = blockIdx.x, t = threadIdx.x;
    int v[4];
    #pragma unroll
    for (int j = 0; j < 4; ++j) {
        int k = 4 * t + j;
        v[j] = (k < P2B) ? chunkhist[(size_t)k * NC + c] : 0;
    }
    int s = v[0] + v[1] + v[2] + v[3];
    __shared__ int sc[256];
    sc[t] = s;
    for (int off = 1; off < 256; off <<= 1) {
        __syncthreads();
        int a = (t >= off) ? sc[t - off] : 0;
        __syncthreads();
        sc[t] += a;
    }
    __syncthreads();
    int run = sc[t] - s;   // exclusive over threads
    #pragma unroll
    for (int j = 0; j < 4; ++j) {
        int k = 4 * t + j;
        if (k < P2B) chunkpre[(size_t)k * NC + c] = run;
        run += v[j];
    }
    if (t == 255) coltotal[c] = run;
}

// ---------------- KB: scan bucket totals -> coarse_off ----------------
__global__ __launch_bounds__(512)
void kb_scan(const int* __restrict__ coltotal, int* __restrict__ coarse_off,
             int* __restrict__ offsets) {
    __shared__ int sh[512];
    int t = threadIdx.x;
    int s = (t < NC) ? coltotal[t] : 0;
    sh[t] = s;
    for (int off = 1; off < 512; off <<= 1) {
        __syncthreads();
        int a = (t >= off) ? sh[t - off] : 0;
        __syncthreads();
        sh[t] += a;
    }
    __syncthreads();
    if (t < NC) coarse_off[t] = sh[t] - s;
    if (t == 0) { coarse_off[NC] = N_EDGES; offsets[N_NODES] = N_EDGES; }
}

// ---------------- P2: chunked scatter, precomputed bases, LDS-staged write-out ----------------
// pack = src | (dst&1023)<<19
__global__ __launch_bounds__(256)
void p2_scatter(const int* __restrict__ src, const int* __restrict__ dst,
                const int* __restrict__ chunkhist, const int* __restrict__ chunkpre,
                const int* __restrict__ coarse_off, int* __restrict__ bc) {
    __shared__ int wbase[NC], cur[NC];
    __shared__ int sc[512];
    __shared__ int sorted[CHUNK];
    __shared__ unsigned short bkt[CHUNK];
    int t = threadIdx.x, k = blockIdx.x;
    int e0 = k * CHUNK;
    int e1 = min(e0 + CHUNK, N_EDGES);
    int ne = e1 - e0;
    // own hist row + scan -> local layout
    int v0 = (t < NC)       ? chunkhist[(size_t)k * NC + t]       : 0;
    int v1 = (t + 256 < NC) ? chunkhist[(size_t)k * NC + t + 256] : 0;
    sc[t] = v0; sc[t + 256] = v1;
    for (int off = 1; off < 512; off <<= 1) {
        __syncthreads();
        int a = (t >= off) ? sc[t - off] : 0;
        int b = (t + 256 >= off) ? sc[t + 256 - off] : 0;
        __syncthreads();
        sc[t] += a; sc[t + 256] += b;
    }
    __syncthreads();
    if (t < NC) {
        int ex = sc[t] - v0;
        cur[t] = ex;
        wbase[t] = coarse_off[t] + chunkpre[(size_t)k * NC + t] - ex;
    }
    if (t + 256 < NC) {
        int ex = sc[t + 256] - v1;
        cur[t + 256] = ex;
        wbase[t + 256] = coarse_off[t + 256] + chunkpre[(size_t)k * NC + t + 256] - ex;
    }
    __syncthreads();
    // scatter into LDS grouped by bucket
    for (int e = e0 + t; e < e1; e += 256) {
        int d = dst[e];
        int cb = d >> 10;
        int r = atomicAdd(&cur[cb], 1);
        sorted[r] = src[e] | ((d & 1023) << 19);
        bkt[r] = (unsigned short)cb;
    }
    __syncthreads();
    // coalesced-ish write-out: consecutive threads -> consecutive addresses per run
    for (int p = t; p < ne; p += 256) {
        bc[wbase[bkt[p]] + p] = sorted[p];
    }
}

// ---------------- P3: node-exact CSR within each coarse bucket ----------------
__global__ __launch_bounds__(256)
void p3_csr(const int* __restrict__ coarse_off, const int* __restrict__ bc,
            int* __restrict__ offsets, int* __restrict__ csr) {
    int c = blockIdx.x;
    int b0 = coarse_off[c], b1 = coarse_off[c + 1];
    __shared__ int h[1024], cur[1024], ts[256];
    int t = threadIdx.x;
    for (int i = t; i < 1024; i += 256) h[i] = 0;
    __syncthreads();
    for (int i = b0 + t; i < b1; i += 256) atomicAdd(&h[(bc[i] >> 19) & 1023], 1);
    __syncthreads();
    int base4 = t * 4;
    int a0 = h[base4], a1 = h[base4 + 1], a2 = h[base4 + 2], a3 = h[base4 + 3];
    int s = a0 + a1 + a2 + a3;
    ts[t] = s;
    for (int off = 1; off < 256; off <<= 1) {
        __syncthreads();
        int v = (t >= off) ? ts[t - off] : 0;
        __syncthreads();
        ts[t] += v;
    }
    __syncthreads();
    int excl = ts[t] - s;
    h[base4]     = excl;
    h[base4 + 1] = excl + a0;
    h[base4 + 2] = excl + a0 + a1;
    h[base4 + 3] = excl + a0 + a1 + a2;
    cur[base4]     = h[base4];
    cur[base4 + 1] = h[base4 + 1];
    cur[base4 + 2] = h[base4 + 2];
    cur[base4 + 3] = h[base4 + 3];
    __syncthreads();
    int node0 = c << 10;
    for (int i = t; i < 1024; i += 256) {
        int n = node0 + i;
        if (n < N_NODES) offsets[n] = b0 + h[i];
    }
    for (int i = b0 + t; i < b1; i += 256) {
        int v = bc[i];
        int loc = (v >> 19) & 1023;
        int p = atomicAdd(&cur[loc], 1);
        csr[b0 + p] = v & 0x7FFFF;
    }
}

// ---------------- combined weights: wc = w0 @ w1[IN:], db = b0 @ w1[IN:] ----------------
__global__ __launch_bounds__(256)
void weights_kernel(const float* w0_1, const float* b0_1, const float* w1_1,
                    const float* w0_2, const float* b0_2, const float* w1_2,
                    const float* w0_3, const float* b0_3, const float* w1_3,
                    float* __restrict__ out) {
    const float *w0, *b0, *w1; int IN;
    if (blockIdx.x == 0)      { w0 = w0_1; b0 = b0_1; w1 = w1_1; IN = 11; }
    else if (blockIdx.x == 1) { w0 = w0_2; b0 = b0_2; w1 = w1_2; IN = 19; }
    else                      { w0 = w0_3; b0 = b0_3; w1 = w1_3; IN = 19; }
    __shared__ float sw0[19 * 19], sw1b[19 * 19], sb0[19];
    int t = threadIdx.x;
    for (int i = t; i < IN * 19; i += 256) sw0[i]  = w0[i];
    for (int i = t; i < 19 * 19; i += 256) sw1b[i] = w1[IN * 19 + i];
    if (t < 19) sb0[t] = b0[t];
    __syncthreads();
    float* o = out + blockIdx.x * 380;
    for (int idx = t; idx < IN * 19; idx += 256) {
        int i = idx / 19, j = idx - 19 * (idx / 19);
        float s = 0.f;
        #pragma unroll
        for (int k = 0; k < 19; ++k) s = fmaf(sw0[i * 19 + k], sw1b[k * 19 + j], s);
        o[idx] = s;
    }
    if (t < 19) {
        float s = 0.f;
        #pragma unroll
        for (int k = 0; k < 19; ++k) s = fmaf(sb0[k], sw1b[k * 19 + t], s);
        o[361 + t] = s;
    }
}

// ---------------- L1: f16 32B-row gather, 4 edge slots x 2 half-rows, 8 lanes/node ----------------
__global__ __launch_bounds__(256)
void fused_layer1(const float* __restrict__ x, const char* __restrict__ xg,
                  const int* __restrict__ csr, const int* __restrict__ offsets,
                  const float* __restrict__ w1, const float* __restrict__ b1,
                  const float* __restrict__ wcdb, char* __restrict__ packout) {
    constexpr int IN = 11;
    __shared__ float sw1a[IN * 19], swc[IN * 19], sdb[19], sb1[19];
    __shared__ float shx[L1NPB][IN], shs[L1NPB][17];
    __shared__ int   sdeg[L1NPB];
    int t = threadIdx.x;
    for (int i = t; i < IN * 19; i += 256) { sw1a[i] = w1[i]; swc[i] = wcdb[i]; }
    if (t < 19) { sdb[t] = wcdb[361 + t]; sb1[t] = b1[t]; }
    int node0 = blockIdx.x * L1NPB;
    for (int idx = t; idx < L1NPB * IN; idx += 256) {
        int nl = idx / IN, i = idx - nl * IN;
        shx[nl][i] = x[(size_t)(node0 + nl) * IN + i];
    }
    int nl = t >> 3;                    // node within block (0..31)
    int l8 = t & 7;
    int slot = l8 >> 1, half = l8 & 1;  // 4 edge slots x 2 half-rows
    int n = node0 + nl;                 // always < N_NODES (500000 = 32*15625)
    float acc[8] = {0.f, 0.f, 0.f, 0.f, 0.f, 0.f, 0.f, 0.f};
    int o0 = offsets[n], o1 = offsets[n + 1];
    // software-pipelined: next csr index loads before the dependent row fetch
    int i = o0 + slot;
    int r0 = (i < o1) ? csr[i] : -1;
    while (r0 >= 0) {
        int i2 = i + 4;
        int r1 = (i2 < o1) ? csr[i2] : -1;
        const float4 v = *(const float4*)(xg + ((size_t)r0 << 5) + (half << 4));
        const __half2* hp = (const __half2*)&v;
        #pragma unroll
        for (int p = 0; p < 4; ++p) {
            float2 f = __half22float2(hp[p]);
            acc[2 * p]     += f.x;
            acc[2 * p + 1] += f.y;
        }
        r0 = r1; i = i2;
    }
    #pragma unroll
    for (int j = 0; j < 8; ++j) {
        acc[j] += __shfl_xor(acc[j], 2);
        acc[j] += __shfl_xor(acc[j], 4);
    }
    if (slot == 0) {                    // l8 in {0,1}
        #pragma unroll
        for (int j = 0; j < 8; ++j) shs[nl][8 * half + j] = acc[j];   // ch 0..15 (11..15 ignored)
        if (half == 0) sdeg[nl] = o1 - o0;
    }
    __syncthreads();
    for (int idx = t; idx < L1NPB * 19; idx += 256) {
        int nl2 = idx / 19, cc = idx - nl2 * 19;
        int n2 = node0 + nl2;
        float v = sb1[cc] + (float)sdeg[nl2] * sdb[cc];
        #pragma unroll
        for (int i2 = 0; i2 < IN; ++i2) v = fmaf(shx[nl2][i2], sw1a[i2 * 19 + cc], v);
        #pragma unroll
        for (int i2 = 0; i2 < IN; ++i2) v = fmaf(shs[nl2][i2], swc[i2 * 19 + cc], v);
        v = fmaxf(v, 0.f);
        char* prow = packout + ((size_t)n2 << 6);
        if (cc < 13) *(float*)(prow + 4 * cc) = v;
        else         *(__half*)(prow + 52 + 2 * (cc - 13)) = __float2half(v);
    }
}

// ---------------- layers 2/3: packed-row self + gather (13 f32 + 6 f16), packed out ----------------
__global__ __launch_bounds__(256)
void fused_layer23(const char* __restrict__ xself, const char* __restrict__ xg,
                   const int* __restrict__ csr, const int* __restrict__ offsets,
                   const float* __restrict__ w1, const float* __restrict__ b1,
                   const float* __restrict__ wcdb, char* __restrict__ packout) {
    constexpr int IN = 19;
    __shared__ float sw1a[IN * 19], swc[IN * 19], sdb[19], sb1[19];
    __shared__ float shx[LNPB][19], shs[LNPB][20];
    __shared__ int   sdeg[LNPB];
    int t = threadIdx.x;
    for (int i = t; i < IN * 19; i += 256) { sw1a[i] = w1[i]; swc[i] = wcdb[i]; }
    if (t < 19) { sdb[t] = wcdb[361 + t]; sb1[t] = b1[t]; }
    int node0 = blockIdx.x * LNPB;
    // self rows from packed buffer (streaming, L2-friendly)
    for (int idx = t; idx < LNPB * 19; idx += 256) {
        int nl = idx / 19, cc = idx - nl * 19;
        const char* prow = xself + ((size_t)(node0 + nl) << 6);
        shx[nl][cc] = (cc < 13) ? *(const float*)(prow + 4 * cc)
                                : __half2float(*(const __half*)(prow + 52 + 2 * (cc - 13)));
    }
    int nl = t >> 4;
    int l16 = t & 15;
    int es = l16 >> 2, k = l16 & 3;
    int n = node0 + nl;
    float acc[8] = {0.f, 0.f, 0.f, 0.f, 0.f, 0.f, 0.f, 0.f};
    int o0 = offsets[n], o1 = offsets[n + 1];
    // software-pipelined csr walk
    int i = o0 + es;
    int r0 = (i < o1) ? csr[i] : -1;
    while (r0 >= 0) {
        int i2 = i + 4;
        int r1 = (i2 < o1) ? csr[i2] : -1;
        const float4 v = *(const float4*)(xg + ((size_t)r0 << 6) + (k << 4));
        if (k == 3) {
            acc[0] += v.x;                          // ch12 (f32)
            const __half2* hp = (const __half2*)&v.y;
            float2 a = __half22float2(hp[0]);
            float2 b = __half22float2(hp[1]);
            float2 c = __half22float2(hp[2]);
            acc[1] += a.x; acc[2] += a.y;
            acc[3] += b.x; acc[4] += b.y;
            acc[5] += c.x; acc[6] += c.y;
        } else {
            acc[0] += v.x; acc[1] += v.y; acc[2] += v.z; acc[3] += v.w;
        }
        r0 = r1; i = i2;
    }
    #pragma unroll
    for (int j = 0; j < 8; ++j) {
        acc[j] += __shfl_xor(acc[j], 4);
        acc[j] += __shfl_xor(acc[j], 8);
    }
    if (es == 0) {
        if (k == 3) {
            shs[nl][12] = acc[0];
            #pragma unroll
            for (int j = 0; j < 6; ++j) shs[nl][13 + j] = acc[1 + j];
        } else {
            #pragma unroll
            for (int j = 0; j < 4; ++j) {
                int ch = 4 * k + j;
                if (ch < 19) shs[nl][ch] = acc[j];
            }
        }
        if (k == 0) sdeg[nl] = o1 - o0;
    }
    __syncthreads();
    for (int idx = t; idx < LNPB * 19; idx += 256) {
        int nl2 = idx / 19, cc = idx - nl2 * 19;
        int n2 = node0 + nl2;
        float v = sb1[cc] + (float)sdeg[nl2] * sdb[cc];
        #pragma unroll
        for (int i2 = 0; i2 < IN; ++i2) v = fmaf(shx[nl2][i2], sw1a[i2 * 19 + cc], v);
        #pragma unroll
        for (int i2 = 0; i2 < IN; ++i2) v = fmaf(shs[nl2][i2], swc[i2 * 19 + cc], v);
        v += shx[nl2][cc];               // residual
        v = fmaxf(v, 0.f);
        char* prow = packout + ((size_t)n2 << 6);
        if (cc < 13) *(float*)(prow + 4 * cc) = v;
        else         *(__half*)(prow + 52 + 2 * (cc - 13)) = __float2half(v);
    }
}

// ---------------- readout (packed input rows) ----------------
__global__ __launch_bounds__(256)
void readout_kernel(const char* __restrict__ pack, const int* __restrict__ pos,
                    const float* __restrict__ w0, const float* __restrict__ b0,
                    const float* __restrict__ w1, const float* __restrict__ b1,
                    float* __restrict__ out) {
    __shared__ float ws[HID * 10 + 10 + 10 + 1];
    for (int i = threadIdx.x; i < 211; i += 256) {
        float v;
        if (i < 190)      v = w0[i];
        else if (i < 200) v = b0[i - 190];
        else if (i < 210) v = w1[i - 200];
        else              v = b1[0];
        ws[i] = v;
    }
    __syncthreads();
    int g = blockIdx.x * 256 + threadIdx.x;
    if (g >= N_GRAPHS) return;
    const char* prow = pack + ((size_t)pos[g] << 6);
    float hv[19];
    #pragma unroll
    for (int i = 0; i < 13; ++i) hv[i] = *(const float*)(prow + 4 * i);
    #pragma unroll
    for (int i = 13; i < 19; ++i) hv[i] = __half2float(*(const __half*)(prow + 52 + 2 * (i - 13)));
    float t[10];
    #pragma unroll
    for (int j = 0; j < 10; ++j) {
        float acc = ws[190 + j];
        #pragma unroll
        for (int i = 0; i < HID; ++i) acc = fmaf(hv[i], ws[i * 10 + j], acc);
        t[j] = fmaxf(acc, 0.0f);
    }
    float o = ws[210];
    #pragma unroll
    for (int j = 0; j < 10; ++j) o = fmaf(t[j], ws[200 + j], o);
    out[g] = fmaxf(o, 0.0f);
}

extern "C" void kernel_launch(void* const* d_in, const int* in_sizes, int n_in,
                              void* d_out, int out_size, void* d_ws, size_t ws_size,
                              hipStream_t stream) {
    const float* x     = (const float*)d_in[0];
    const int*   ei    = (const int*)d_in[1];
    const int*   batch = (const int*)d_in[2];
    const float* w0_1 = (const float*)d_in[3];
    const float* b0_1 = (const float*)d_in[4];
    const float* w1_1 = (const float*)d_in[5];
    const float* b1_1 = (const float*)d_in[6];
    const float* w0_2 = (const float*)d_in[7];
    const float* b0_2 = (const float*)d_in[8];
    const float* w1_2 = (const float*)d_in[9];
    const float* b1_2 = (const float*)d_in[10];
    const float* w0_3 = (const float*)d_in[11];
    const float* b0_3 = (const float*)d_in[12];
    const float* w1_3 = (const float*)d_in[13];
    const float* b1_3 = (const float*)d_in[14];
    const float* wfc0 = (const float*)d_in[15];
    const float* bfc0 = (const float*)d_in[16];
    const float* wfc1 = (const float*)d_in[17];
    const float* bfc1 = (const float*)d_in[18];

    const int* src = ei;            // edge_index[0]
    const int* dst = ei + N_EDGES;  // edge_index[1]

    char* ws = (char*)d_ws;
    size_t off = 0;
    auto alloc = [&](size_t bytes) { void* p = ws + off; off = (off + bytes + 511) & ~(size_t)511; return p; };
    char*  SCRATCH   = (char*) alloc((size_t)N_EDGES * 4);         // 32 MB: bc (sort), later PACK2
    char*  PACK1     = (char*) alloc((size_t)N_NODES * 64);        // 32 MB: L1 out / L2 gather; later L3 out
    char*  XP        = (char*) alloc((size_t)N_NODES * 32);        // 16 MB: L1 f16 gather rows
    int*   csr       = (int*)  alloc((size_t)N_EDGES * 4);         // 32 MB
    int*   offsets   = (int*)  alloc(((size_t)N_NODES + 1) * 4);
    int*   chunkhist = (int*)  alloc((size_t)P2B * NC * 4);        // 1.9 MB
    int*   chunkpre  = (int*)  alloc((size_t)P2B * NC * 4);        // 1.9 MB
    int*   coarse_off= (int*)  alloc((NC + 1) * 4);
    int*   coltotal  = (int*)  alloc(NC * 4);
    int*   pos       = (int*)  alloc((size_t)N_GRAPHS * 4);
    float* wcdb      = (float*)alloc(3 * 380 * 4);
    int*   bc        = (int*)SCRATCH;
    char*  PACK2     = SCRATCH;     // bc dead after p3; L2 out / L3 gather+self
    char*  PACK3     = PACK1;       // PACK1 content dead after L2 -> L3 out

    dim3 blk(256);
    int gridN  = (N_NODES + 255) / 256;
    int gridL1 = N_NODES / L1NPB;            // 15625, exact
    int gridL  = N_NODES / LNPB;             // 31250, exact
    int gridG  = (N_GRAPHS + 255) / 256;

    weights_kernel<<<3, blk, 0, stream>>>(w0_1, b0_1, w1_1, w0_2, b0_2, w1_2,
                                          w0_3, b0_3, w1_3, wcdb);
    prep_kernel<<<gridN, blk, 0, stream>>>(x, (__half*)XP, batch, pos);

    // ---- bucket sort -> node-exact CSR (deterministic bases, no global atomics) ----
    p1_hist<<<P2B, blk, 0, stream>>>(dst, chunkhist);
    ka_chunkscan<<<NC, blk, 0, stream>>>(chunkhist, chunkpre, coltotal);
    kb_scan<<<1, 512, 0, stream>>>(coltotal, coarse_off, offsets);
    p2_scatter<<<P2B, blk, 0, stream>>>(src, dst, chunkhist, chunkpre, coarse_off, bc);
    p3_csr<<<NC, blk, 0, stream>>>(coarse_off, bc, offsets, csr);

    // ---- 3 fused layers, packed 64B inter-layer rows ----
    fused_layer1<<<gridL1, blk, 0, stream>>>(
        x, XP, csr, offsets, w1_1, b1_1, wcdb, PACK1);
    fused_layer23<<<gridL, blk, 0, stream>>>(
        PACK1, PACK1, csr, offsets, w1_2, b1_2, wcdb + 380, PACK2);
    fused_layer23<<<gridL, blk, 0, stream>>>(
        PACK2, PACK2, csr, offsets, w1_3, b1_3, wcdb + 760, PACK3);

    // ---- Readout ----
    readout_kernel<<<gridG, blk, 0, stream>>>(PACK3, pos, wfc0, bfc0, wfc1, bfc1,
                                              (float*)d_out);
}

// Round 12
// 578.010 us; speedup vs baseline: 1.7525x; 1.0420x over previous
//
#include <hip/hip_runtime.h>
#include <hip/hip_fp16.h>

constexpr int N_NODES  = 500000;
constexpr int N_EDGES  = 8000000;
constexpr int N_GRAPHS = 25000;
constexpr int HID      = 19;

constexpr int NC    = (N_NODES + 1023) / 1024;   // 489 coarse buckets (dst>>10)
constexpr int CHUNK = 8192;                      // edges per sort chunk
constexpr int P2B   = (N_EDGES + CHUNK - 1) / CHUNK;  // 977 chunks
constexpr int LNPB  = 16;                        // nodes per 256-thread L2/L3 block
constexpr int L1NPB = 64;                        // nodes per 256-thread L1 block (4 lanes/node)

// ---------------- prep: x (11ch f32) -> xp rows (32B: 11 f16 + pad) + pos ----------------
__global__ __launch_bounds__(256)
void prep_kernel(const float* __restrict__ x, __half* __restrict__ xp,
                 const int* __restrict__ batch, int* __restrict__ pos) {
    int i = blockIdx.x * 256 + threadIdx.x;
    if (i >= N_NODES) return;
    int b  = batch[i];
    int nb = (i == N_NODES - 1) ? N_GRAPHS : batch[i + 1];
    for (int g = b; g < nb; ++g) pos[g] = i;
    if (i == 0) {
        for (int g = 0; g < b; ++g) pos[g] = N_NODES - 1;   // JAX -1 wrap
    }
    const float* xs = x + (size_t)i * 11;
    __half hrow[16];
    #pragma unroll
    for (int k = 0; k < 11; ++k) hrow[k] = __float2half(xs[k]);
    #pragma unroll
    for (int k = 11; k < 16; ++k) hrow[k] = __half(0.0f);
    int4* xd = (int4*)(xp + (size_t)i * 16);
    xd[0] = ((const int4*)hrow)[0];
    xd[1] = ((const int4*)hrow)[1];
}

// ---------------- P1: per-chunk coarse histograms (int4 edge reads) ----------------
__global__ __launch_bounds__(256)
void p1_hist(const int* __restrict__ dst, int* __restrict__ chunkhist) {
    __shared__ int h[NC];
    int t = threadIdx.x, k = blockIdx.x;
    for (int i = t; i < NC; i += 256) h[i] = 0;
    __syncthreads();
    int e0 = k * CHUNK;
    int e1 = min(e0 + CHUNK, N_EDGES);
    for (int e = e0 + 4 * t; e < e1; e += 1024) {
        int4 d4 = *(const int4*)(dst + e);
        atomicAdd(&h[d4.x >> 10], 1);
        atomicAdd(&h[d4.y >> 10], 1);
        atomicAdd(&h[d4.z >> 10], 1);
        atomicAdd(&h[d4.w >> 10], 1);
    }
    __syncthreads();
    for (int i = t; i < NC; i += 256) chunkhist[(size_t)k * NC + i] = h[i];
}

// ---------------- KA: per-bucket exclusive scan across chunks ----------------
__global__ __launch_bounds__(256)
void ka_chunkscan(const int* __restrict__ chunkhist, int* __restrict__ chunkpre,
                  int* __restrict__ coltotal) {
    int c = blockIdx.x, t = threadIdx.x;
    int v[4];
    #pragma unroll
    for (int j = 0; j < 4; ++j) {
        int k = 4 * t + j;
        v[j] = (k < P2B) ? chunkhist[(size_t)k * NC + c] : 0;
    }
    int s = v[0] + v[1] + v[2] + v[3];
    __shared__ int sc[256];
    sc[t] = s;
    for (int off = 1; off < 256; off <<= 1) {
        __syncthreads();
        int a = (t >= off) ? sc[t - off] : 0;
        __syncthreads();
        sc[t] += a;
    }
    __syncthreads();
    int run = sc[t] - s;   // exclusive over threads
    #pragma unroll
    for (int j = 0; j < 4; ++j) {
        int k = 4 * t + j;
        if (k < P2B) chunkpre[(size_t)k * NC + c] = run;
        run += v[j];
    }
    if (t == 255) coltotal[c] = run;
}

// ---------------- KB: scan bucket totals -> coarse_off ----------------
__global__ __launch_bounds__(512)
void kb_scan(const int* __restrict__ coltotal, int* __restrict__ coarse_off,
             int* __restrict__ offsets) {
    __shared__ int sh[512];
    int t = threadIdx.x;
    int s = (t < NC) ? coltotal[t] : 0;
    sh[t] = s;
    for (int off = 1; off < 512; off <<= 1) {
        __syncthreads();
        int a = (t >= off) ? sh[t - off] : 0;
        __syncthreads();
        sh[t] += a;
    }
    __syncthreads();
    if (t < NC) coarse_off[t] = sh[t] - s;
    if (t == 0) { coarse_off[NC] = N_EDGES; offsets[N_NODES] = N_EDGES; }
}

// ---------------- P2: chunked scatter, precomputed bases, LDS-staged write-out ----------------
// pack = src | (dst&1023)<<19
__global__ __launch_bounds__(256)
void p2_scatter(const int* __restrict__ src, const int* __restrict__ dst,
                const int* __restrict__ chunkhist, const int* __restrict__ chunkpre,
                const int* __restrict__ coarse_off, int* __restrict__ bc) {
    __shared__ int wbase[NC], cur[NC];
    __shared__ int sc[512];
    __shared__ int sorted[CHUNK];
    __shared__ unsigned short bkt[CHUNK];
    int t = threadIdx.x, k = blockIdx.x;
    int e0 = k * CHUNK;
    int e1 = min(e0 + CHUNK, N_EDGES);
    int ne = e1 - e0;
    // own hist row + scan -> local layout
    int v0 = (t < NC)       ? chunkhist[(size_t)k * NC + t]       : 0;
    int v1 = (t + 256 < NC) ? chunkhist[(size_t)k * NC + t + 256] : 0;
    sc[t] = v0; sc[t + 256] = v1;
    for (int off = 1; off < 512; off <<= 1) {
        __syncthreads();
        int a = (t >= off) ? sc[t - off] : 0;
        int b = (t + 256 >= off) ? sc[t + 256 - off] : 0;
        __syncthreads();
        sc[t] += a; sc[t + 256] += b;
    }
    __syncthreads();
    if (t < NC) {
        int ex = sc[t] - v0;
        cur[t] = ex;
        wbase[t] = coarse_off[t] + chunkpre[(size_t)k * NC + t] - ex;
    }
    if (t + 256 < NC) {
        int ex = sc[t + 256] - v1;
        cur[t + 256] = ex;
        wbase[t + 256] = coarse_off[t + 256] + chunkpre[(size_t)k * NC + t + 256] - ex;
    }
    __syncthreads();
    // scatter into LDS grouped by bucket (int4 edge reads)
    for (int e = e0 + 4 * t; e < e1; e += 1024) {
        int4 d4 = *(const int4*)(dst + e);
        int4 s4 = *(const int4*)(src + e);
        int cb, r;
        cb = d4.x >> 10; r = atomicAdd(&cur[cb], 1);
        sorted[r] = s4.x | ((d4.x & 1023) << 19); bkt[r] = (unsigned short)cb;
        cb = d4.y >> 10; r = atomicAdd(&cur[cb], 1);
        sorted[r] = s4.y | ((d4.y & 1023) << 19); bkt[r] = (unsigned short)cb;
        cb = d4.z >> 10; r = atomicAdd(&cur[cb], 1);
        sorted[r] = s4.z | ((d4.z & 1023) << 19); bkt[r] = (unsigned short)cb;
        cb = d4.w >> 10; r = atomicAdd(&cur[cb], 1);
        sorted[r] = s4.w | ((d4.w & 1023) << 19); bkt[r] = (unsigned short)cb;
    }
    __syncthreads();
    // coalesced-ish write-out: consecutive threads -> consecutive addresses per run
    for (int p = t; p < ne; p += 256) {
        bc[wbase[bkt[p]] + p] = sorted[p];
    }
}

// ---------------- P3: node-exact CSR within each coarse bucket ----------------
__global__ __launch_bounds__(256)
void p3_csr(const int* __restrict__ coarse_off, const int* __restrict__ bc,
            int* __restrict__ offsets, int* __restrict__ csr) {
    int c = blockIdx.x;
    int b0 = coarse_off[c], b1 = coarse_off[c + 1];
    __shared__ int h[1024], cur[1024], ts[256];
    int t = threadIdx.x;
    for (int i = t; i < 1024; i += 256) h[i] = 0;
    __syncthreads();
    for (int i = b0 + t; i < b1; i += 256) atomicAdd(&h[(bc[i] >> 19) & 1023], 1);
    __syncthreads();
    int base4 = t * 4;
    int a0 = h[base4], a1 = h[base4 + 1], a2 = h[base4 + 2], a3 = h[base4 + 3];
    int s = a0 + a1 + a2 + a3;
    ts[t] = s;
    for (int off = 1; off < 256; off <<= 1) {
        __syncthreads();
        int v = (t >= off) ? ts[t - off] : 0;
        __syncthreads();
        ts[t] += v;
    }
    __syncthreads();
    int excl = ts[t] - s;
    h[base4]     = excl;
    h[base4 + 1] = excl + a0;
    h[base4 + 2] = excl + a0 + a1;
    h[base4 + 3] = excl + a0 + a1 + a2;
    cur[base4]     = h[base4];
    cur[base4 + 1] = h[base4 + 1];
    cur[base4 + 2] = h[base4 + 2];
    cur[base4 + 3] = h[base4 + 3];
    __syncthreads();
    int node0 = c << 10;
    for (int i = t; i < 1024; i += 256) {
        int n = node0 + i;
        if (n < N_NODES) offsets[n] = b0 + h[i];
    }
    for (int i = b0 + t; i < b1; i += 256) {
        int v = bc[i];
        int loc = (v >> 19) & 1023;
        int p = atomicAdd(&cur[loc], 1);
        csr[b0 + p] = v & 0x7FFFF;
    }
}

// ---------------- combined weights: wc = w0 @ w1[IN:], db = b0 @ w1[IN:] ----------------
__global__ __launch_bounds__(256)
void weights_kernel(const float* w0_1, const float* b0_1, const float* w1_1,
                    const float* w0_2, const float* b0_2, const float* w1_2,
                    const float* w0_3, const float* b0_3, const float* w1_3,
                    float* __restrict__ out) {
    const float *w0, *b0, *w1; int IN;
    if (blockIdx.x == 0)      { w0 = w0_1; b0 = b0_1; w1 = w1_1; IN = 11; }
    else if (blockIdx.x == 1) { w0 = w0_2; b0 = b0_2; w1 = w1_2; IN = 19; }
    else                      { w0 = w0_3; b0 = b0_3; w1 = w1_3; IN = 19; }
    __shared__ float sw0[19 * 19], sw1b[19 * 19], sb0[19];
    int t = threadIdx.x;
    for (int i = t; i < IN * 19; i += 256) sw0[i]  = w0[i];
    for (int i = t; i < 19 * 19; i += 256) sw1b[i] = w1[IN * 19 + i];
    if (t < 19) sb0[t] = b0[t];
    __syncthreads();
    float* o = out + blockIdx.x * 380;
    for (int idx = t; idx < IN * 19; idx += 256) {
        int i = idx / 19, j = idx - 19 * (idx / 19);
        float s = 0.f;
        #pragma unroll
        for (int k = 0; k < 19; ++k) s = fmaf(sw0[i * 19 + k], sw1b[k * 19 + j], s);
        o[idx] = s;
    }
    if (t < 19) {
        float s = 0.f;
        #pragma unroll
        for (int k = 0; k < 19; ++k) s = fmaf(sb0[k], sw1b[k * 19 + t], s);
        o[361 + t] = s;
    }
}

// ---------------- L1: f16 32B-row gather, 2 edge slots x 2 half-rows, 4 lanes/node ----------------
__global__ __launch_bounds__(256)
void fused_layer1(const float* __restrict__ x, const char* __restrict__ xg,
                  const int* __restrict__ csr, const int* __restrict__ offsets,
                  const float* __restrict__ w1, const float* __restrict__ b1,
                  const float* __restrict__ wcdb, char* __restrict__ packout) {
    constexpr int IN = 11;
    __shared__ float sw1a[IN * 19], swc[IN * 19], sdb[19], sb1[19];
    __shared__ float shx[L1NPB][IN], shs[L1NPB][17];
    __shared__ int   sdeg[L1NPB];
    int t = threadIdx.x;
    for (int i = t; i < IN * 19; i += 256) { sw1a[i] = w1[i]; swc[i] = wcdb[i]; }
    if (t < 19) { sdb[t] = wcdb[361 + t]; sb1[t] = b1[t]; }
    int node0 = blockIdx.x * L1NPB;
    for (int idx = t; idx < L1NPB * IN; idx += 256) {
        int nl = idx / IN, i = idx - nl * IN;
        int n1 = node0 + nl;
        shx[nl][i] = (n1 < N_NODES) ? x[(size_t)n1 * IN + i] : 0.f;
    }
    int nl = t >> 2;                    // node within block (0..63)
    int l4 = t & 3;
    int slot = l4 >> 1, half = l4 & 1;  // 2 edge slots x 2 half-rows
    int n = node0 + nl;
    float acc[8] = {0.f, 0.f, 0.f, 0.f, 0.f, 0.f, 0.f, 0.f};
    int o0 = 0, o1 = 0;
    if (n < N_NODES) { o0 = offsets[n]; o1 = offsets[n + 1]; }
    // software-pipelined: next csr index loads before the dependent row fetch
    int i = o0 + slot;
    int r0 = (i < o1) ? csr[i] : -1;
    while (r0 >= 0) {
        int i2 = i + 2;
        int r1 = (i2 < o1) ? csr[i2] : -1;
        const float4 v = *(const float4*)(xg + ((size_t)r0 << 5) + (half << 4));
        const __half2* hp = (const __half2*)&v;
        #pragma unroll
        for (int p = 0; p < 4; ++p) {
            float2 f = __half22float2(hp[p]);
            acc[2 * p]     += f.x;
            acc[2 * p + 1] += f.y;
        }
        r0 = r1; i = i2;
    }
    #pragma unroll
    for (int j = 0; j < 8; ++j) {
        acc[j] += __shfl_xor(acc[j], 2);   // fold the 2 edge slots
    }
    if (slot == 0 && n < N_NODES) {        // l4 in {0,1}
        #pragma unroll
        for (int j = 0; j < 8; ++j) shs[nl][8 * half + j] = acc[j];   // ch 0..15 (11..15 ignored)
        if (half == 0) sdeg[nl] = o1 - o0;
    }
    __syncthreads();
    for (int idx = t; idx < L1NPB * 19; idx += 256) {
        int nl2 = idx / 19, cc = idx - nl2 * 19;
        int n2 = node0 + nl2;
        if (n2 >= N_NODES) continue;
        float v = sb1[cc] + (float)sdeg[nl2] * sdb[cc];
        #pragma unroll
        for (int i2 = 0; i2 < IN; ++i2) v = fmaf(shx[nl2][i2], sw1a[i2 * 19 + cc], v);
        #pragma unroll
        for (int i2 = 0; i2 < IN; ++i2) v = fmaf(shs[nl2][i2], swc[i2 * 19 + cc], v);
        v = fmaxf(v, 0.f);
        char* prow = packout + ((size_t)n2 << 6);
        if (cc < 13) *(float*)(prow + 4 * cc) = v;
        else         *(__half*)(prow + 52 + 2 * (cc - 13)) = __float2half(v);
    }
}

// ---------------- layers 2/3: packed-row self + gather (13 f32 + 6 f16), packed out ----------------
__global__ __launch_bounds__(256)
void fused_layer23(const char* __restrict__ xself, const char* __restrict__ xg,
                   const int* __restrict__ csr, const int* __restrict__ offsets,
                   const float* __restrict__ w1, const float* __restrict__ b1,
                   const float* __restrict__ wcdb, char* __restrict__ packout) {
    constexpr int IN = 19;
    __shared__ float sw1a[IN * 19], swc[IN * 19], sdb[19], sb1[19];
    __shared__ float shx[LNPB][19], shs[LNPB][20];
    __shared__ int   sdeg[LNPB];
    int t = threadIdx.x;
    for (int i = t; i < IN * 19; i += 256) { sw1a[i] = w1[i]; swc[i] = wcdb[i]; }
    if (t < 19) { sdb[t] = wcdb[361 + t]; sb1[t] = b1[t]; }
    int node0 = blockIdx.x * LNPB;
    // self rows from packed buffer (streaming, L2-friendly)
    for (int idx = t; idx < LNPB * 19; idx += 256) {
        int nl = idx / 19, cc = idx - nl * 19;
        const char* prow = xself + ((size_t)(node0 + nl) << 6);
        shx[nl][cc] = (cc < 13) ? *(const float*)(prow + 4 * cc)
                                : __half2float(*(const __half*)(prow + 52 + 2 * (cc - 13)));
    }
    int nl = t >> 4;
    int l16 = t & 15;
    int es = l16 >> 2, k = l16 & 3;
    int n = node0 + nl;
    float acc[8] = {0.f, 0.f, 0.f, 0.f, 0.f, 0.f, 0.f, 0.f};
    int o0 = offsets[n], o1 = offsets[n + 1];
    // software-pipelined csr walk
    int i = o0 + es;
    int r0 = (i < o1) ? csr[i] : -1;
    while (r0 >= 0) {
        int i2 = i + 4;
        int r1 = (i2 < o1) ? csr[i2] : -1;
        const float4 v = *(const float4*)(xg + ((size_t)r0 << 6) + (k << 4));
        if (k == 3) {
            acc[0] += v.x;                          // ch12 (f32)
            const __half2* hp = (const __half2*)&v.y;
            float2 a = __half22float2(hp[0]);
            float2 b = __half22float2(hp[1]);
            float2 c = __half22float2(hp[2]);
            acc[1] += a.x; acc[2] += a.y;
            acc[3] += b.x; acc[4] += b.y;
            acc[5] += c.x; acc[6] += c.y;
        } else {
            acc[0] += v.x; acc[1] += v.y; acc[2] += v.z; acc[3] += v.w;
        }
        r0 = r1; i = i2;
    }
    #pragma unroll
    for (int j = 0; j < 8; ++j) {
        acc[j] += __shfl_xor(acc[j], 4);
        acc[j] += __shfl_xor(acc[j], 8);
    }
    if (es == 0) {
        if (k == 3) {
            shs[nl][12] = acc[0];
            #pragma unroll
            for (int j = 0; j < 6; ++j) shs[nl][13 + j] = acc[1 + j];
        } else {
            #pragma unroll
            for (int j = 0; j < 4; ++j) {
                int ch = 4 * k + j;
                if (ch < 19) shs[nl][ch] = acc[j];
            }
        }
        if (k == 0) sdeg[nl] = o1 - o0;
    }
    __syncthreads();
    for (int idx = t; idx < LNPB * 19; idx += 256) {
        int nl2 = idx / 19, cc = idx - nl2 * 19;
        int n2 = node0 + nl2;
        float v = sb1[cc] + (float)sdeg[nl2] * sdb[cc];
        #pragma unroll
        for (int i2 = 0; i2 < IN; ++i2) v = fmaf(shx[nl2][i2], sw1a[i2 * 19 + cc], v);
        #pragma unroll
        for (int i2 = 0; i2 < IN; ++i2) v = fmaf(shs[nl2][i2], swc[i2 * 19 + cc], v);
        v += shx[nl2][cc];               // residual
        v = fmaxf(v, 0.f);
        char* prow = packout + ((size_t)n2 << 6);
        if (cc < 13) *(float*)(prow + 4 * cc) = v;
        else         *(__half*)(prow + 52 + 2 * (cc - 13)) = __float2half(v);
    }
}

// ---------------- readout (packed input rows) ----------------
__global__ __launch_bounds__(256)
void readout_kernel(const char* __restrict__ pack, const int* __restrict__ pos,
                    const float* __restrict__ w0, const float* __restrict__ b0,
                    const float* __restrict__ w1, const float* __restrict__ b1,
                    float* __restrict__ out) {
    __shared__ float ws[HID * 10 + 10 + 10 + 1];
    for (int i = threadIdx.x; i < 211; i += 256) {
        float v;
        if (i < 190)      v = w0[i];
        else if (i < 200) v = b0[i - 190];
        else if (i < 210) v = w1[i - 200];
        else              v = b1[0];
        ws[i] = v;
    }
    __syncthreads();
    int g = blockIdx.x * 256 + threadIdx.x;
    if (g >= N_GRAPHS) return;
    const char* prow = pack + ((size_t)pos[g] << 6);
    float hv[19];
    #pragma unroll
    for (int i = 0; i < 13; ++i) hv[i] = *(const float*)(prow + 4 * i);
    #pragma unroll
    for (int i = 13; i < 19; ++i) hv[i] = __half2float(*(const __half*)(prow + 52 + 2 * (i - 13)));
    float t[10];
    #pragma unroll
    for (int j = 0; j < 10; ++j) {
        float acc = ws[190 + j];
        #pragma unroll
        for (int i = 0; i < HID; ++i) acc = fmaf(hv[i], ws[i * 10 + j], acc);
        t[j] = fmaxf(acc, 0.0f);
    }
    float o = ws[210];
    #pragma unroll
    for (int j = 0; j < 10; ++j) o = fmaf(t[j], ws[200 + j], o);
    out[g] = fmaxf(o, 0.0f);
}

extern "C" void kernel_launch(void* const* d_in, const int* in_sizes, int n_in,
                              void* d_out, int out_size, void* d_ws, size_t ws_size,
                              hipStream_t stream) {
    const float* x     = (const float*)d_in[0];
    const int*   ei    = (const int*)d_in[1];
    const int*   batch = (const int*)d_in[2];
    const float* w0_1 = (const float*)d_in[3];
    const float* b0_1 = (const float*)d_in[4];
    const float* w1_1 = (const float*)d_in[5];
    const float* b1_1 = (const float*)d_in[6];
    const float* w0_2 = (const float*)d_in[7];
    const float* b0_2 = (const float*)d_in[8];
    const float* w1_2 = (const float*)d_in[9];
    const float* b1_2 = (const float*)d_in[10];
    const float* w0_3 = (const float*)d_in[11];
    const float* b0_3 = (const float*)d_in[12];
    const float* w1_3 = (const float*)d_in[13];
    const float* b1_3 = (const float*)d_in[14];
    const float* wfc0 = (const float*)d_in[15];
    const float* bfc0 = (const float*)d_in[16];
    const float* wfc1 = (const float*)d_in[17];
    const float* bfc1 = (const float*)d_in[18];

    const int* src = ei;            // edge_index[0]
    const int* dst = ei + N_EDGES;  // edge_index[1]

    char* ws = (char*)d_ws;
    size_t off = 0;
    auto alloc = [&](size_t bytes) { void* p = ws + off; off = (off + bytes + 511) & ~(size_t)511; return p; };
    char*  SCRATCH   = (char*) alloc((size_t)N_EDGES * 4);         // 32 MB: bc (sort), later PACK2
    char*  PACK1     = (char*) alloc((size_t)N_NODES * 64);        // 32 MB: L1 out / L2 gather; later L3 out
    char*  XP        = (char*) alloc((size_t)N_NODES * 32);        // 16 MB: L1 f16 gather rows
    int*   csr       = (int*)  alloc((size_t)N_EDGES * 4);         // 32 MB
    int*   offsets   = (int*)  alloc(((size_t)N_NODES + 1) * 4);
    int*   chunkhist = (int*)  alloc((size_t)P2B * NC * 4);        // 1.9 MB
    int*   chunkpre  = (int*)  alloc((size_t)P2B * NC * 4);        // 1.9 MB
    int*   coarse_off= (int*)  alloc((NC + 1) * 4);
    int*   coltotal  = (int*)  alloc(NC * 4);
    int*   pos       = (int*)  alloc((size_t)N_GRAPHS * 4);
    float* wcdb      = (float*)alloc(3 * 380 * 4);
    int*   bc        = (int*)SCRATCH;
    char*  PACK2     = SCRATCH;     // bc dead after p3; L2 out / L3 gather+self
    char*  PACK3     = PACK1;       // PACK1 content dead after L2 -> L3 out

    dim3 blk(256);
    int gridN  = (N_NODES + 255) / 256;
    int gridL1 = (N_NODES + L1NPB - 1) / L1NPB;   // 7813
    int gridL  = N_NODES / LNPB;                  // 31250, exact
    int gridG  = (N_GRAPHS + 255) / 256;

    weights_kernel<<<3, blk, 0, stream>>>(w0_1, b0_1, w1_1, w0_2, b0_2, w1_2,
                                          w0_3, b0_3, w1_3, wcdb);
    prep_kernel<<<gridN, blk, 0, stream>>>(x, (__half*)XP, batch, pos);

    // ---- bucket sort -> node-exact CSR (deterministic bases, no global atomics) ----
    p1_hist<<<P2B, blk, 0, stream>>>(dst, chunkhist);
    ka_chunkscan<<<NC, blk, 0, stream>>>(chunkhist, chunkpre, coltotal);
    kb_scan<<<1, 512, 0, stream>>>(coltotal, coarse_off, offsets);
    p2_scatter<<<P2B, blk, 0, stream>>>(src, dst, chunkhist, chunkpre, coarse_off, bc);
    p3_csr<<<NC, blk, 0, stream>>>(coarse_off, bc, offsets, csr);

    // ---- 3 fused layers, packed 64B inter-layer rows ----
    fused_layer1<<<gridL1, blk, 0, stream>>>(
        x, XP, csr, offsets, w1_1, b1_1, wcdb, PACK1);
    fused_layer23<<<gridL, blk, 0, stream>>>(
        PACK1, PACK1, csr, offsets, w1_2, b1_2, wcdb + 380, PACK2);
    fused_layer23<<<gridL, blk, 0, stream>>>(
        PACK2, PACK2, csr, offsets, w1_3, b1_3, wcdb + 760, PACK3);

    // ---- Readout ----
    readout_kernel<<<gridG, blk, 0, stream>>>(PACK3, pos, wfc0, bfc0, wfc1, bfc1,
                                              (float*)d_out);
}